// Round 1
// baseline (1851.888 us; speedup 1.0000x reference)
//
#include <hip/hip_runtime.h>
#include <math.h>

#define NN 10000           // nodes
#define NB 4               // batch
#define NE 160000          // edges
#define DM 256             // model dim
#define MR (NB * NN)       // 40000 flattened rows
#define LN_EPS 1e-5f
#define WCHUNK 250         // node chunk for reductions (40 chunks * 250 = 10000)

// ---------------- helpers ----------------

__device__ inline float gelu_exact(float x) {
    return 0.5f * x * (1.0f + erff(x * 0.70710678118654752f));
}

__device__ inline float waveReduce(float v) {
#pragma unroll
    for (int off = 32; off > 0; off >>= 1) v += __shfl_down(v, off, 64);
    return v;
}

// ---------------- utility kernels ----------------

__global__ void zero_f32_kernel(float* p, int n) {
    int i = blockIdx.x * 256 + threadIdx.x;
    if (i < n) p[i] = 0.0f;
}

__global__ void zero_i32_kernel(int* p, int n) {
    int i = blockIdx.x * 256 + threadIdx.x;
    if (i < n) p[i] = 0;
}

// ---------------- CSR build ----------------

__global__ void hist_kernel(const int* __restrict__ dst, int* __restrict__ counts, int e) {
    int i = blockIdx.x * 256 + threadIdx.x;
    if (i < e) atomicAdd(&counts[dst[i]], 1);
}

__global__ __launch_bounds__(256) void scan_kernel(const int* __restrict__ counts,
                                                   int* __restrict__ row_ptr,
                                                   int* __restrict__ fill_pos, int n) {
    __shared__ int sums[256];
    int tid = threadIdx.x;
    int chunk = (n + 255) / 256;
    int s0 = tid * chunk;
    int s1 = min(n, s0 + chunk);
    int local = 0;
    for (int i = s0; i < s1; i++) local += counts[i];
    sums[tid] = local;
    __syncthreads();
    for (int off = 1; off < 256; off <<= 1) {
        int v = (tid >= off) ? sums[tid - off] : 0;
        __syncthreads();
        sums[tid] += v;
        __syncthreads();
    }
    int base = (tid == 0) ? 0 : sums[tid - 1];
    for (int i = s0; i < s1; i++) {
        row_ptr[i] = base;
        fill_pos[i] = base;
        base += counts[i];
    }
    if (tid == 255) row_ptr[n] = sums[255];
}

__global__ void fill_kernel(const int* __restrict__ src, const int* __restrict__ dst,
                            int* __restrict__ fill_pos, int* __restrict__ csr_src, int e) {
    int i = blockIdx.x * 256 + threadIdx.x;
    if (i < e) {
        int p = atomicAdd(&fill_pos[dst[i]], 1);
        csr_src[p] = src[i];
    }
}

// ---------------- GEMM: C = act(A[MxK] @ W[KxNc] + bias) ----------------
// Requires M%64==0, K%16==0, Nc%64==0. act: 0=none, 1=relu

__global__ __launch_bounds__(256) void gemm_kernel(const float* __restrict__ A,
                                                   const float* __restrict__ W,
                                                   const float* __restrict__ bias,
                                                   float* __restrict__ C,
                                                   int M, int K, int Nc, int act) {
    __shared__ float As[16][65];
    __shared__ __align__(16) float Bs[16][64];
    const int tid = threadIdx.x;
    const int bm0 = blockIdx.y * 64;
    const int bn0 = blockIdx.x * 64;
    const int ty = tid >> 4, tx = tid & 15;
    const int ty4 = ty * 4, tx4 = tx * 4;
    const int a_row = tid >> 2;
    const int a_col = (tid & 3) * 4;
    const int b_row = tid >> 4;
    const int b_col = (tid & 15) * 4;

    float acc[4][4] = {};

    for (int k0 = 0; k0 < K; k0 += 16) {
        float4 av = *(const float4*)(A + (size_t)(bm0 + a_row) * K + k0 + a_col);
        float4 bv = *(const float4*)(W + (size_t)(k0 + b_row) * Nc + bn0 + b_col);
        As[a_col + 0][a_row] = av.x;
        As[a_col + 1][a_row] = av.y;
        As[a_col + 2][a_row] = av.z;
        As[a_col + 3][a_row] = av.w;
        *(float4*)&Bs[b_row][b_col] = bv;
        __syncthreads();
#pragma unroll
        for (int k = 0; k < 16; k++) {
            const float a0 = As[k][ty4 + 0];
            const float a1 = As[k][ty4 + 1];
            const float a2 = As[k][ty4 + 2];
            const float a3 = As[k][ty4 + 3];
            const float4 b4 = *(const float4*)&Bs[k][tx4];
            acc[0][0] += a0 * b4.x; acc[0][1] += a0 * b4.y; acc[0][2] += a0 * b4.z; acc[0][3] += a0 * b4.w;
            acc[1][0] += a1 * b4.x; acc[1][1] += a1 * b4.y; acc[1][2] += a1 * b4.z; acc[1][3] += a1 * b4.w;
            acc[2][0] += a2 * b4.x; acc[2][1] += a2 * b4.y; acc[2][2] += a2 * b4.z; acc[2][3] += a2 * b4.w;
            acc[3][0] += a3 * b4.x; acc[3][1] += a3 * b4.y; acc[3][2] += a3 * b4.z; acc[3][3] += a3 * b4.w;
        }
        __syncthreads();
    }

    float bx = 0, by = 0, bz = 0, bw = 0;
    if (bias) {
        bx = bias[bn0 + tx4 + 0];
        by = bias[bn0 + tx4 + 1];
        bz = bias[bn0 + tx4 + 2];
        bw = bias[bn0 + tx4 + 3];
    }
#pragma unroll
    for (int i = 0; i < 4; i++) {
        int row = bm0 + ty4 + i;
        float4 o;
        o.x = acc[i][0] + bx;
        o.y = acc[i][1] + by;
        o.z = acc[i][2] + bz;
        o.w = acc[i][3] + bw;
        if (act == 1) {
            o.x = fmaxf(o.x, 0.0f); o.y = fmaxf(o.y, 0.0f);
            o.z = fmaxf(o.z, 0.0f); o.w = fmaxf(o.w, 0.0f);
        }
        *(float4*)(C + (size_t)row * Nc + bn0 + tx4) = o;
    }
}

// ---------------- GCN aggregation: out = gelu(segsum(sup[src]) + bias) ----------------

__global__ __launch_bounds__(256) void agg_bias_gelu_kernel(const float* __restrict__ sup,
                                                            const int* __restrict__ row_ptr,
                                                            const int* __restrict__ csr_src,
                                                            const float* __restrict__ bias,
                                                            float* __restrict__ out) {
    int n = blockIdx.x, b = blockIdx.y, h = threadIdx.x;
    int s = row_ptr[n], e = row_ptr[n + 1];
    const float* supb = sup + (size_t)b * NN * DM;
    float acc = 0.0f;
    for (int j = s; j < e; j++) {
        acc += supb[(size_t)csr_src[j] * DM + h];
    }
    out[((size_t)b * NN + n) * DM + h] = gelu_exact(acc + bias[h]);
}

// ---------------- attention pooling ----------------

// a[idx] = sum_j tanh( (x_row @ W)[j] ) * u[j] ; W: 256x8, u: 8
__global__ __launch_bounds__(256) void attn_score_kernel(const float* __restrict__ x,
                                                         const float* __restrict__ W,
                                                         const float* __restrict__ u,
                                                         float* __restrict__ a) {
    int lane = threadIdx.x & 63, wv = threadIdx.x >> 6;
    int idx = blockIdx.x * 4 + wv;
    const float4 xv = *(const float4*)(x + (size_t)idx * DM + lane * 4);
    const float4* Wv = (const float4*)W;
    int d0 = lane * 4;
    float xs[4] = {xv.x, xv.y, xv.z, xv.w};
    float t[8] = {0, 0, 0, 0, 0, 0, 0, 0};
#pragma unroll
    for (int dd = 0; dd < 4; dd++) {
        float4 w0 = Wv[(d0 + dd) * 2 + 0];
        float4 w1 = Wv[(d0 + dd) * 2 + 1];
        t[0] += xs[dd] * w0.x; t[1] += xs[dd] * w0.y; t[2] += xs[dd] * w0.z; t[3] += xs[dd] * w0.w;
        t[4] += xs[dd] * w1.x; t[5] += xs[dd] * w1.y; t[6] += xs[dd] * w1.z; t[7] += xs[dd] * w1.w;
    }
#pragma unroll
    for (int j = 0; j < 8; j++) t[j] = waveReduce(t[j]);
    if (lane == 0) {
        float s = 0.0f;
#pragma unroll
        for (int j = 0; j < 8; j++) s += tanhf(t[j]) * u[j];
        a[idx] = s;
    }
}

// s[idx] = x_row . r[b]
__global__ __launch_bounds__(256) void dot_r_kernel(const float* __restrict__ x,
                                                    const float* __restrict__ r,
                                                    float* __restrict__ s) {
    int lane = threadIdx.x & 63, wv = threadIdx.x >> 6;
    int idx = blockIdx.x * 4 + wv;
    int b = idx / NN;
    float4 xv = *(const float4*)(x + (size_t)idx * DM + lane * 4);
    float4 rv = *(const float4*)(r + (size_t)b * DM + lane * 4);
    float acc = xv.x * rv.x + xv.y * rv.y + xv.z * rv.z + xv.w * rv.w;
    acc = waveReduce(acc);
    if (lane == 0) s[idx] = acc;
}

// softmax over N per batch
__global__ __launch_bounds__(256) void softmax_kernel(const float* __restrict__ a,
                                                      float* __restrict__ alpha) {
    int b = blockIdx.x;
    const float* ab = a + (size_t)b * NN;
    float* ob = alpha + (size_t)b * NN;
    __shared__ float red[256];
    int tid = threadIdx.x;
    float m = -INFINITY;
    for (int i = tid; i < NN; i += 256) m = fmaxf(m, ab[i]);
    red[tid] = m;
    __syncthreads();
    for (int off = 128; off > 0; off >>= 1) {
        if (tid < off) red[tid] = fmaxf(red[tid], red[tid + off]);
        __syncthreads();
    }
    m = red[0];
    __syncthreads();
    float sum = 0.0f;
    for (int i = tid; i < NN; i += 256) sum += expf(ab[i] - m);
    red[tid] = sum;
    __syncthreads();
    for (int off = 128; off > 0; off >>= 1) {
        if (tid < off) red[tid] += red[tid + off];
        __syncthreads();
    }
    float inv = 1.0f / red[0];
    for (int i = tid; i < NN; i += 256) ob[i] = expf(ab[i] - m) * inv;
}

// r[b,d] += sum_{n in chunk} w[b,n] * x[b,n,d]
__global__ __launch_bounds__(256) void wsum_kernel(const float* __restrict__ w,
                                                   const float* __restrict__ x,
                                                   float* __restrict__ r) {
    int b = blockIdx.y, c = blockIdx.x, d = threadIdx.x;
    int n0 = c * WCHUNK, n1 = n0 + WCHUNK;
    const float* wb = w + (size_t)b * NN;
    const float* xb = x + (size_t)b * NN * DM;
    float acc = 0.0f;
    for (int n = n0; n < n1; n++) acc += wb[n] * xb[(size_t)n * DM + d];
    atomicAdd(&r[b * DM + d], acc);
}

// ---------------- LayerNorm (wave per row) ----------------

__global__ __launch_bounds__(256) void ln_bcast_kernel(const float* __restrict__ x,
                                                       const float* __restrict__ r,
                                                       const float* __restrict__ g,
                                                       const float* __restrict__ bt,
                                                       float* __restrict__ out) {
    int lane = threadIdx.x & 63, wv = threadIdx.x >> 6;
    int row = blockIdx.x * 4 + wv;
    int b = row / NN;
    float4 xv = *(const float4*)(x + (size_t)row * DM + lane * 4);
    float4 rv = *(const float4*)(r + (size_t)b * DM + lane * 4);
    float4 y;
    y.x = xv.x + rv.x; y.y = xv.y + rv.y; y.z = xv.z + rv.z; y.w = xv.w + rv.w;
    float s = y.x + y.y + y.z + y.w;
    float sq = y.x * y.x + y.y * y.y + y.z * y.z + y.w * y.w;
    s = waveReduce(s);
    sq = waveReduce(sq);
    s = __shfl(s, 0, 64);
    sq = __shfl(sq, 0, 64);
    float mean = s * (1.0f / 256.0f);
    float var = sq * (1.0f / 256.0f) - mean * mean;
    float rstd = rsqrtf(var + LN_EPS);
    float4 gv = *(const float4*)(g + lane * 4);
    float4 bv = *(const float4*)(bt + lane * 4);
    float4 o;
    o.x = (y.x - mean) * rstd * gv.x + bv.x;
    o.y = (y.y - mean) * rstd * gv.y + bv.y;
    o.z = (y.z - mean) * rstd * gv.z + bv.z;
    o.w = (y.w - mean) * rstd * gv.w + bv.w;
    *(float4*)(out + (size_t)row * DM + lane * 4) = o;
}

__global__ __launch_bounds__(256) void ln_elem_kernel(const float* __restrict__ x,
                                                      const float* __restrict__ h,
                                                      const float* __restrict__ g,
                                                      const float* __restrict__ bt,
                                                      float* __restrict__ out) {
    int lane = threadIdx.x & 63, wv = threadIdx.x >> 6;
    int row = blockIdx.x * 4 + wv;
    float4 xv = *(const float4*)(x + (size_t)row * DM + lane * 4);
    float4 hv = *(const float4*)(h + (size_t)row * DM + lane * 4);
    float4 y;
    y.x = xv.x + hv.x; y.y = xv.y + hv.y; y.z = xv.z + hv.z; y.w = xv.w + hv.w;
    float s = y.x + y.y + y.z + y.w;
    float sq = y.x * y.x + y.y * y.y + y.z * y.z + y.w * y.w;
    s = waveReduce(s);
    sq = waveReduce(sq);
    s = __shfl(s, 0, 64);
    sq = __shfl(sq, 0, 64);
    float mean = s * (1.0f / 256.0f);
    float var = sq * (1.0f / 256.0f) - mean * mean;
    float rstd = rsqrtf(var + LN_EPS);
    float4 gv = *(const float4*)(g + lane * 4);
    float4 bv = *(const float4*)(bt + lane * 4);
    float4 o;
    o.x = (y.x - mean) * rstd * gv.x + bv.x;
    o.y = (y.y - mean) * rstd * gv.y + bv.y;
    o.z = (y.z - mean) * rstd * gv.z + bv.z;
    o.w = (y.w - mean) * rstd * gv.w + bv.w;
    *(float4*)(out + (size_t)row * DM + lane * 4) = o;
}

// ---------------- final projection ----------------

__global__ __launch_bounds__(256) void colsum_kernel(const float* __restrict__ x,
                                                     float* __restrict__ cs) {
    int b = blockIdx.y, c = blockIdx.x, d = threadIdx.x;
    int n0 = c * WCHUNK, n1 = n0 + WCHUNK;
    const float* xb = x + (size_t)b * NN * DM;
    float acc = 0.0f;
    for (int n = n0; n < n1; n++) acc += xb[(size_t)n * DM + d];
    atomicAdd(&cs[b * DM + d], acc);
}

__global__ __launch_bounds__(64) void final_kernel(const float* __restrict__ cs,
                                                   const float* __restrict__ fcW,
                                                   const float* __restrict__ fcb,
                                                   float* __restrict__ out) {
    int b = blockIdx.x;
    int o = threadIdx.x;
    if (o < 10) {
        float acc = 0.0f;
        for (int d = 0; d < DM; d++) acc += cs[b * DM + d] * fcW[d * 10 + o];
        out[b * 10 + o] = acc * (1.0f / NN) + fcb[o];
    }
}

// ---------------- launch ----------------

extern "C" void kernel_launch(void* const* d_in, const int* in_sizes, int n_in,
                              void* d_out, int out_size, void* d_ws, size_t ws_size,
                              hipStream_t stream) {
    const float* x_in    = (const float*)d_in[0];
    const int*   src     = (const int*)d_in[1];
    const int*   dst     = (const int*)d_in[2];
    const float* W_conv0 = (const float*)d_in[3];
    const float* b_conv0 = (const float*)d_in[4];
    const float* W_convs = (const float*)d_in[5];
    const float* b_convs = (const float*)d_in[6];
    const float* mW1 = (const float*)d_in[7];
    const float* mb1 = (const float*)d_in[8];
    const float* mW2 = (const float*)d_in[9];
    const float* mb2 = (const float*)d_in[10];
    const float* mW3 = (const float*)d_in[11];
    const float* mb3 = (const float*)d_in[12];
    const float* ln1_g = (const float*)d_in[13];
    const float* ln1_b = (const float*)d_in[14];
    const float* ln2_g = (const float*)d_in[15];
    const float* ln2_b = (const float*)d_in[16];
    const float* attnW = (const float*)d_in[17];
    const float* attnu = (const float*)d_in[18];
    const float* fW1 = (const float*)d_in[19];
    const float* fb1 = (const float*)d_in[20];
    const float* fW2 = (const float*)d_in[21];
    const float* fb2 = (const float*)d_in[22];
    const float* fcW = (const float*)d_in[23];
    const float* fcb = (const float*)d_in[24];
    float* out = (float*)d_out;

    const size_t BIG = (size_t)MR * DM;
    float* A       = (float*)d_ws;
    float* Bb      = A + BIG;
    float* Cc      = Bb + BIG;
    float* a_score = Cc + BIG;
    float* alpha   = a_score + MR;
    float* r       = alpha + MR;
    float* colsum  = r + NB * DM;
    int* counts   = (int*)(colsum + NB * DM);
    int* row_ptr  = counts + NN;
    int* fill_pos = row_ptr + NN + 1;
    int* csr_src  = fill_pos + NN;

    // ---- CSR build (by dst) ----
    zero_i32_kernel<<<(NN + 255) / 256, 256, 0, stream>>>(counts, NN);
    hist_kernel<<<(NE + 255) / 256, 256, 0, stream>>>(dst, counts, NE);
    scan_kernel<<<1, 256, 0, stream>>>(counts, row_ptr, fill_pos, NN);
    fill_kernel<<<(NE + 255) / 256, 256, 0, stream>>>(src, dst, fill_pos, csr_src, NE);

    const dim3 blk(256);
    const dim3 gemm256(4, MR / 64);
    const dim3 aggGrid(NN, NB);

    // ---- GCN layer 0 (F_in=128) ----
    gemm_kernel<<<gemm256, blk, 0, stream>>>(x_in, W_conv0, nullptr, Bb, MR, 128, 256, 0);
    agg_bias_gelu_kernel<<<aggGrid, blk, 0, stream>>>(Bb, row_ptr, csr_src, b_conv0, A);
    // ---- GCN layers 1..3 ----
    for (int i = 0; i < 3; i++) {
        gemm_kernel<<<gemm256, blk, 0, stream>>>(A, W_convs + (size_t)i * 256 * 256, nullptr, Bb,
                                                 MR, 256, 256, 0);
        agg_bias_gelu_kernel<<<aggGrid, blk, 0, stream>>>(Bb, row_ptr, csr_src,
                                                          b_convs + (size_t)i * 256, A);
    }

    // ---- MLP ----
    gemm_kernel<<<dim3(2, MR / 64), blk, 0, stream>>>(A, mW1, mb1, Bb, MR, 256, 128, 1);
    gemm_kernel<<<dim3(1, MR / 64), blk, 0, stream>>>(Bb, mW2, mb2, Cc, MR, 128, 64, 1);
    gemm_kernel<<<gemm256, blk, 0, stream>>>(Cc, mW3, mb3, A, MR, 64, 256, 0);

    // ---- 2 attention/FFN blocks; x lives in A at loop entry ----
    for (int i = 0; i < 2; i++) {
        const float* Wp = attnW + (size_t)i * DM * 8;
        const float* up = attnu + (size_t)i * 8;
        attn_score_kernel<<<MR / 4, blk, 0, stream>>>(A, Wp, up, a_score);
        softmax_kernel<<<NB, blk, 0, stream>>>(a_score, alpha);
        zero_f32_kernel<<<4, blk, 0, stream>>>(r, NB * DM);
        wsum_kernel<<<dim3(NN / WCHUNK, NB), blk, 0, stream>>>(alpha, A, r);
        for (int it = 0; it < 3; it++) {
            dot_r_kernel<<<MR / 4, blk, 0, stream>>>(A, r, a_score);
            softmax_kernel<<<NB, blk, 0, stream>>>(a_score, alpha);
            zero_f32_kernel<<<4, blk, 0, stream>>>(r, NB * DM);
            wsum_kernel<<<dim3(NN / WCHUNK, NB), blk, 0, stream>>>(alpha, A, r);
        }
        // x = LN(x + r) -> Bb
        ln_bcast_kernel<<<MR / 4, blk, 0, stream>>>(A, r, ln1_g + (size_t)i * DM,
                                                    ln1_b + (size_t)i * DM, Bb);
        // h1 = relu(x @ fW1 + fb1) -> Cc
        gemm_kernel<<<gemm256, blk, 0, stream>>>(Bb, fW1 + (size_t)i * DM * DM,
                                                 fb1 + (size_t)i * DM, Cc, MR, 256, 256, 1);
        // h2 = h1 @ fW2 + fb2 -> A
        gemm_kernel<<<gemm256, blk, 0, stream>>>(Cc, fW2 + (size_t)i * DM * DM,
                                                 fb2 + (size_t)i * DM, A, MR, 256, 256, 0);
        // x = LN(x + h2) -> A
        ln_elem_kernel<<<MR / 4, blk, 0, stream>>>(Bb, A, ln2_g + (size_t)i * DM,
                                                   ln2_b + (size_t)i * DM, A);
    }

    // ---- final: mean over nodes commutes with linear layer ----
    zero_f32_kernel<<<4, blk, 0, stream>>>(colsum, NB * DM);
    colsum_kernel<<<dim3(NN / WCHUNK, NB), blk, 0, stream>>>(A, colsum);
    final_kernel<<<NB, dim3(64), 0, stream>>>(colsum, fcW, fcb, out);
}

// Round 2
// 977.928 us; speedup vs baseline: 1.8937x; 1.8937x over previous
//
#include <hip/hip_runtime.h>
#include <math.h>

#define NN 10000           // nodes
#define NB 4               // batch
#define NE 160000          // edges
#define DM 256             // model dim
#define MR (NB * NN)       // 40000 flattened rows
#define LN_EPS 1e-5f
#define WCHUNK 250         // node chunk (40 chunks * 250 = 10000)
#define NCH (NN / WCHUNK)  // 40

typedef __attribute__((ext_vector_type(8))) short short8;
typedef __attribute__((ext_vector_type(4))) float floatx4;

// ---------------- helpers ----------------

__device__ inline float bf2f(unsigned short u) {
    unsigned int x = ((unsigned int)u) << 16;
    float f;
    __builtin_memcpy(&f, &x, 4);
    return f;
}

__device__ inline unsigned short f2bf(float f) {
    unsigned int x;
    __builtin_memcpy(&x, &f, 4);
    unsigned int r = x + 0x7FFFu + ((x >> 16) & 1u);
    return (unsigned short)(r >> 16);
}

__device__ inline float gelu_exact(float x) {
    return 0.5f * x * (1.0f + erff(x * 0.70710678118654752f));
}

__device__ inline float waveAllReduce(float v) {
#pragma unroll
    for (int off = 32; off > 0; off >>= 1) v += __shfl_xor(v, off, 64);
    return v;
}

// ---------------- utility kernels ----------------

__global__ void zero_f32_kernel(float* p, int n) {
    int i = blockIdx.x * 256 + threadIdx.x;
    if (i < n) p[i] = 0.0f;
}

__global__ void zero_i32_kernel(int* p, int n) {
    int i = blockIdx.x * 256 + threadIdx.x;
    if (i < n) p[i] = 0;
}

__global__ void cvt_bf16_kernel(const float* __restrict__ in, unsigned short* __restrict__ out, int n) {
    int i = blockIdx.x * 256 + threadIdx.x;
    if (i < n) out[i] = f2bf(in[i]);
}

// batched weight transpose+convert: Wt[n*K+k] = bf16(W[k*N+n])
struct TD { const float* src; unsigned short* dst; int K; int N; };
struct TDs { TD d[11]; };

__global__ void transpose_all_kernel(TDs tds) {
    TD t = tds.d[blockIdx.y];
    int idx = blockIdx.x * 256 + threadIdx.x;
    int total = t.K * t.N;
    if (idx < total) {
        int n = idx / t.K;
        int k = idx - n * t.K;
        t.dst[idx] = f2bf(t.src[(size_t)k * t.N + n]);
    }
}

// ---------------- CSR build ----------------

__global__ void hist_kernel(const int* __restrict__ dst, int* __restrict__ counts, int e) {
    int i = blockIdx.x * 256 + threadIdx.x;
    if (i < e) atomicAdd(&counts[dst[i]], 1);
}

__global__ __launch_bounds__(256) void scan_kernel(const int* __restrict__ counts,
                                                   int* __restrict__ row_ptr,
                                                   int* __restrict__ fill_pos, int n) {
    __shared__ int sums[256];
    int tid = threadIdx.x;
    int chunk = (n + 255) / 256;
    int s0 = tid * chunk;
    int s1 = min(n, s0 + chunk);
    int local = 0;
    for (int i = s0; i < s1; i++) local += counts[i];
    sums[tid] = local;
    __syncthreads();
    for (int off = 1; off < 256; off <<= 1) {
        int v = (tid >= off) ? sums[tid - off] : 0;
        __syncthreads();
        sums[tid] += v;
        __syncthreads();
    }
    int base = (tid == 0) ? 0 : sums[tid - 1];
    for (int i = s0; i < s1; i++) {
        row_ptr[i] = base;
        fill_pos[i] = base;
        base += counts[i];
    }
    if (tid == 255) row_ptr[n] = sums[255];
}

__global__ void fill_kernel(const int* __restrict__ src, const int* __restrict__ dst,
                            int* __restrict__ fill_pos, int* __restrict__ csr_src, int e) {
    int i = blockIdx.x * 256 + threadIdx.x;
    if (i < e) {
        int p = atomicAdd(&fill_pos[dst[i]], 1);
        csr_src[p] = src[i];
    }
}

// ---------------- MFMA GEMM ----------------
// C = act(A[MxK]bf16 @ B[KxN] + bias), B given transposed bf16 as Bt[N][K].
// BM=64, BN in {64,128}. Block 256 = 4 waves (2x2), wave tile 32 x (BN/2).
// LDS layout is fragment-ordered: chunk (blk,lane) holds
// X[blk*16 + (lane&15)][k0 + (lane>>4)*8 .. +8]  -> ds_read_b128 lane-linear.

template <int BN>
__global__ __launch_bounds__(256) void mfma_gemm_kernel(
    const unsigned short* __restrict__ A, const unsigned short* __restrict__ Bt,
    const float* __restrict__ bias, float* __restrict__ Cf,
    unsigned short* __restrict__ Cb, int M, int K, int N, int act) {
    constexpr int NBF = BN / 32;   // b-frags per wave (4 for BN=128, 2 for BN=64)
    __shared__ unsigned short AsL[4 * 64 * 8];            // 4KB
    __shared__ unsigned short BsL[(BN / 16) * 64 * 8];    // 8KB / 4KB

    const int tid = threadIdx.x;
    const int w = tid >> 6, l = tid & 63;
    const int wm = w >> 1, wn = w & 1;
    const int bm0 = blockIdx.y * 64;
    const int bn0 = blockIdx.x * BN;
    const int lm = l & 15, lq = l >> 4;

    floatx4 acc[2][NBF];
#pragma unroll
    for (int mi = 0; mi < 2; mi++)
#pragma unroll
        for (int ni = 0; ni < NBF; ni++) acc[mi][ni] = (floatx4){0.f, 0.f, 0.f, 0.f};

    // staging addresses (row part constant over k-loop)
    const int s_mb = tid >> 6, s_ll = tid & 63;
    const int a_row = bm0 + s_mb * 16 + (s_ll & 15);
    const int s_kc = (s_ll >> 4) * 8;

    for (int k0 = 0; k0 < K; k0 += 32) {
        *(short8*)&AsL[tid * 8] = *(const short8*)&A[(size_t)a_row * K + k0 + s_kc];
#pragma unroll
        for (int cc = 0; cc < BN / 64; cc++) {
            int c = tid + cc * 256;
            int nb = c >> 6;
            int ll = c & 63;
            int rown = bn0 + nb * 16 + (ll & 15);
            int kc = k0 + (ll >> 4) * 8;
            *(short8*)&BsL[c * 8] = *(const short8*)&Bt[(size_t)rown * K + kc];
        }
        __syncthreads();
        short8 af[2], bfv[NBF];
#pragma unroll
        for (int mi = 0; mi < 2; mi++) af[mi] = *(short8*)&AsL[((wm * 2 + mi) * 64 + l) * 8];
#pragma unroll
        for (int ni = 0; ni < NBF; ni++) bfv[ni] = *(short8*)&BsL[((wn * NBF + ni) * 64 + l) * 8];
#pragma unroll
        for (int mi = 0; mi < 2; mi++)
#pragma unroll
            for (int ni = 0; ni < NBF; ni++)
                acc[mi][ni] = __builtin_amdgcn_mfma_f32_16x16x32_bf16(af[mi], bfv[ni], acc[mi][ni], 0, 0, 0);
        __syncthreads();
    }

#pragma unroll
    for (int ni = 0; ni < NBF; ni++) {
        int col = bn0 + (wn * NBF + ni) * 16 + lm;
        float bv = bias ? bias[col] : 0.0f;
#pragma unroll
        for (int mi = 0; mi < 2; mi++) {
            int row0 = bm0 + (wm * 2 + mi) * 16 + lq * 4;
#pragma unroll
            for (int r = 0; r < 4; r++) {
                float v = acc[mi][ni][r] + bv;
                if (act == 1) v = fmaxf(v, 0.0f);
                size_t off = (size_t)(row0 + r) * N + col;
                if (Cf) Cf[off] = v;
                if (Cb) Cb[off] = f2bf(v);
            }
        }
    }
}

// ---------------- GCN aggregation (bf16 in/out, fp32 acc) ----------------
// block = node, 4 waves = 4 batches; lane covers 4 dims via ushort4.

__global__ __launch_bounds__(256) void agg_kernel(const unsigned short* __restrict__ sup,
                                                  const int* __restrict__ row_ptr,
                                                  const int* __restrict__ csr_src,
                                                  const float* __restrict__ bias,
                                                  unsigned short* __restrict__ out) {
    int n = blockIdx.x;
    int b = threadIdx.x >> 6, l = threadIdx.x & 63;
    int s = row_ptr[n], e = row_ptr[n + 1];
    const unsigned short* base = sup + (size_t)b * NN * DM;
    float a0 = 0.f, a1 = 0.f, a2 = 0.f, a3 = 0.f;
    int j = s;
    for (; j + 4 <= e; j += 4) {
        int s0 = csr_src[j], s1 = csr_src[j + 1], s2 = csr_src[j + 2], s3 = csr_src[j + 3];
        ushort4 v0 = *(const ushort4*)&base[(size_t)s0 * DM + l * 4];
        ushort4 v1 = *(const ushort4*)&base[(size_t)s1 * DM + l * 4];
        ushort4 v2 = *(const ushort4*)&base[(size_t)s2 * DM + l * 4];
        ushort4 v3 = *(const ushort4*)&base[(size_t)s3 * DM + l * 4];
        a0 += bf2f(v0.x) + bf2f(v1.x) + bf2f(v2.x) + bf2f(v3.x);
        a1 += bf2f(v0.y) + bf2f(v1.y) + bf2f(v2.y) + bf2f(v3.y);
        a2 += bf2f(v0.z) + bf2f(v1.z) + bf2f(v2.z) + bf2f(v3.z);
        a3 += bf2f(v0.w) + bf2f(v1.w) + bf2f(v2.w) + bf2f(v3.w);
    }
    for (; j < e; j++) {
        ushort4 v = *(const ushort4*)&base[(size_t)csr_src[j] * DM + l * 4];
        a0 += bf2f(v.x); a1 += bf2f(v.y); a2 += bf2f(v.z); a3 += bf2f(v.w);
    }
    const float4 bv = *(const float4*)&bias[l * 4];
    ushort4 o;
    o.x = f2bf(gelu_exact(a0 + bv.x));
    o.y = f2bf(gelu_exact(a1 + bv.y));
    o.z = f2bf(gelu_exact(a2 + bv.z));
    o.w = f2bf(gelu_exact(a3 + bv.w));
    *(ushort4*)&out[((size_t)b * NN + n) * DM + l * 4] = o;
}

// ---------------- attention pooling ----------------

// a[idx] = sum_j tanh( (x_row @ W)[j] ) * u[j] ; W: 256x8, u: 8 ; x bf16
__global__ __launch_bounds__(256) void attn_score_kernel(const unsigned short* __restrict__ x16,
                                                         const float* __restrict__ W,
                                                         const float* __restrict__ u,
                                                         float* __restrict__ a) {
    int l = threadIdx.x & 63, w = threadIdx.x >> 6;
    int idx = blockIdx.x * 4 + w;
    ushort4 xb = *(const ushort4*)&x16[(size_t)idx * DM + l * 4];
    float xs[4] = {bf2f(xb.x), bf2f(xb.y), bf2f(xb.z), bf2f(xb.w)};
    const float4* Wv = (const float4*)W;
    int d0 = l * 4;
    float t[8] = {0, 0, 0, 0, 0, 0, 0, 0};
#pragma unroll
    for (int dd = 0; dd < 4; dd++) {
        float4 w0 = Wv[(d0 + dd) * 2 + 0];
        float4 w1 = Wv[(d0 + dd) * 2 + 1];
        t[0] += xs[dd] * w0.x; t[1] += xs[dd] * w0.y; t[2] += xs[dd] * w0.z; t[3] += xs[dd] * w0.w;
        t[4] += xs[dd] * w1.x; t[5] += xs[dd] * w1.y; t[6] += xs[dd] * w1.z; t[7] += xs[dd] * w1.w;
    }
#pragma unroll
    for (int j = 0; j < 8; j++) t[j] = waveAllReduce(t[j]);
    if (l == 0) {
        float s = 0.0f;
#pragma unroll
        for (int j = 0; j < 8; j++) s += tanhf(t[j]) * u[j];
        a[idx] = s;
    }
}

// fused online-softmax weighted sum over a node chunk.
// mode 0: s = a_score[row]; mode 1: s = x_row . r[b]
__global__ __launch_bounds__(256) void attn_pool_kernel(const unsigned short* __restrict__ x16,
                                                        const float* __restrict__ a_score,
                                                        const float* __restrict__ r, int mode,
                                                        float* __restrict__ pm,
                                                        float* __restrict__ pl,
                                                        float* __restrict__ pv) {
    int c = blockIdx.x, b = blockIdx.y;
    int w = threadIdx.x >> 6, l = threadIdx.x & 63;
    int n0 = c * WCHUNK, n1 = n0 + WCHUNK;
    float4 rv = {0, 0, 0, 0};
    if (mode) rv = *(const float4*)&r[b * DM + l * 4];
    float m = -INFINITY, L = 0.0f;
    float v0 = 0.f, v1 = 0.f, v2 = 0.f, v3 = 0.f;
    for (int n = n0 + w; n < n1; n += 4) {
        ushort4 xb = *(const ushort4*)&x16[((size_t)b * NN + n) * DM + l * 4];
        float x0 = bf2f(xb.x), x1 = bf2f(xb.y), x2 = bf2f(xb.z), x3 = bf2f(xb.w);
        float s;
        if (mode) {
            s = x0 * rv.x + x1 * rv.y + x2 * rv.z + x3 * rv.w;
            s = waveAllReduce(s);
        } else {
            s = a_score[b * NN + n];
        }
        if (s > m) {  // wave-uniform branch
            float sc = __expf(m - s);
            L *= sc; v0 *= sc; v1 *= sc; v2 *= sc; v3 *= sc;
            m = s;
        }
        float wgt = __expf(s - m);
        L += wgt;
        v0 += wgt * x0; v1 += wgt * x1; v2 += wgt * x2; v3 += wgt * x3;
    }
    __shared__ float sm[4], sl[4];
    __shared__ float sv[4][DM];
    if (l == 0) { sm[w] = m; sl[w] = L; }
    float4 vv = {v0, v1, v2, v3};
    *(float4*)&sv[w][l * 4] = vv;
    __syncthreads();
    int d = threadIdx.x;
    float M = fmaxf(fmaxf(sm[0], sm[1]), fmaxf(sm[2], sm[3]));
    float e0 = __expf(sm[0] - M), e1 = __expf(sm[1] - M);
    float e2 = __expf(sm[2] - M), e3 = __expf(sm[3] - M);
    float Lt = e0 * sl[0] + e1 * sl[1] + e2 * sl[2] + e3 * sl[3];
    float vd = e0 * sv[0][d] + e1 * sv[1][d] + e2 * sv[2][d] + e3 * sv[3][d];
    pv[((size_t)b * NCH + c) * DM + d] = vd;
    if (d == 0) {
        pm[b * NCH + c] = M;
        pl[b * NCH + c] = Lt;
    }
}

__global__ __launch_bounds__(256) void attn_combine_kernel(const float* __restrict__ pm,
                                                           const float* __restrict__ pl,
                                                           const float* __restrict__ pv,
                                                           float* __restrict__ r) {
    int b = blockIdx.x, d = threadIdx.x;
    float M = -INFINITY;
    for (int c = 0; c < NCH; c++) M = fmaxf(M, pm[b * NCH + c]);
    float L = 0.0f;
    for (int c = 0; c < NCH; c++) L += __expf(pm[b * NCH + c] - M) * pl[b * NCH + c];
    float acc = 0.0f;
    for (int c = 0; c < NCH; c++)
        acc += __expf(pm[b * NCH + c] - M) * pv[((size_t)b * NCH + c) * DM + d];
    r[b * DM + d] = acc / L;
}

// ---------------- LayerNorm ----------------

// out_bf16 = LN(x + r[b]) ; x fp32
__global__ __launch_bounds__(256) void ln_bcast_kernel(const float* __restrict__ x,
                                                       const float* __restrict__ r,
                                                       const float* __restrict__ g,
                                                       const float* __restrict__ bt,
                                                       unsigned short* __restrict__ out16) {
    int l = threadIdx.x & 63, w = threadIdx.x >> 6;
    int row = blockIdx.x * 4 + w;
    int b = row / NN;
    float4 xv = *(const float4*)(x + (size_t)row * DM + l * 4);
    float4 rv = *(const float4*)(r + (size_t)b * DM + l * 4);
    float4 y;
    y.x = xv.x + rv.x; y.y = xv.y + rv.y; y.z = xv.z + rv.z; y.w = xv.w + rv.w;
    float s = y.x + y.y + y.z + y.w;
    float sq = y.x * y.x + y.y * y.y + y.z * y.z + y.w * y.w;
    s = waveAllReduce(s);
    sq = waveAllReduce(sq);
    float mean = s * (1.0f / 256.0f);
    float var = sq * (1.0f / 256.0f) - mean * mean;
    float rstd = rsqrtf(var + LN_EPS);
    float4 gv = *(const float4*)(g + l * 4);
    float4 bv = *(const float4*)(bt + l * 4);
    ushort4 o;
    o.x = f2bf((y.x - mean) * rstd * gv.x + bv.x);
    o.y = f2bf((y.y - mean) * rstd * gv.y + bv.y);
    o.z = f2bf((y.z - mean) * rstd * gv.z + bv.z);
    o.w = f2bf((y.w - mean) * rstd * gv.w + bv.w);
    *(ushort4*)&out16[(size_t)row * DM + l * 4] = o;
}

// out_f32 = LN(x16 + h) ; also writes bf16 copy
__global__ __launch_bounds__(256) void ln_elem_kernel(const unsigned short* __restrict__ x16,
                                                      const float* __restrict__ h,
                                                      const float* __restrict__ g,
                                                      const float* __restrict__ bt,
                                                      float* __restrict__ out,
                                                      unsigned short* __restrict__ out16) {
    int l = threadIdx.x & 63, w = threadIdx.x >> 6;
    int row = blockIdx.x * 4 + w;
    ushort4 xb = *(const ushort4*)&x16[(size_t)row * DM + l * 4];
    float4 hv = *(const float4*)(h + (size_t)row * DM + l * 4);
    float4 y;
    y.x = bf2f(xb.x) + hv.x; y.y = bf2f(xb.y) + hv.y;
    y.z = bf2f(xb.z) + hv.z; y.w = bf2f(xb.w) + hv.w;
    float s = y.x + y.y + y.z + y.w;
    float sq = y.x * y.x + y.y * y.y + y.z * y.z + y.w * y.w;
    s = waveAllReduce(s);
    sq = waveAllReduce(sq);
    float mean = s * (1.0f / 256.0f);
    float var = sq * (1.0f / 256.0f) - mean * mean;
    float rstd = rsqrtf(var + LN_EPS);
    float4 gv = *(const float4*)(g + l * 4);
    float4 bv = *(const float4*)(bt + l * 4);
    float4 o;
    o.x = (y.x - mean) * rstd * gv.x + bv.x;
    o.y = (y.y - mean) * rstd * gv.y + bv.y;
    o.z = (y.z - mean) * rstd * gv.z + bv.z;
    o.w = (y.w - mean) * rstd * gv.w + bv.w;
    *(float4*)(out + (size_t)row * DM + l * 4) = o;
    ushort4 o16;
    o16.x = f2bf(o.x); o16.y = f2bf(o.y); o16.z = f2bf(o.z); o16.w = f2bf(o.w);
    *(ushort4*)&out16[(size_t)row * DM + l * 4] = o16;
}

// ---------------- final projection ----------------

__global__ __launch_bounds__(256) void colsum_kernel(const float* __restrict__ x,
                                                     float* __restrict__ cs) {
    int b = blockIdx.y, c = blockIdx.x, d = threadIdx.x;
    int n0 = c * WCHUNK, n1 = n0 + WCHUNK;
    const float* xb = x + (size_t)b * NN * DM;
    float acc = 0.0f;
    for (int n = n0; n < n1; n++) acc += xb[(size_t)n * DM + d];
    atomicAdd(&cs[b * DM + d], acc);
}

__global__ __launch_bounds__(64) void final_kernel(const float* __restrict__ cs,
                                                   const float* __restrict__ fcW,
                                                   const float* __restrict__ fcb,
                                                   float* __restrict__ out) {
    int b = blockIdx.x;
    int o = threadIdx.x;
    if (o < 10) {
        float acc = 0.0f;
        for (int d = 0; d < DM; d++) acc += cs[b * DM + d] * fcW[d * 10 + o];
        out[b * 10 + o] = acc * (1.0f / NN) + fcb[o];
    }
}

// ---------------- launch ----------------

extern "C" void kernel_launch(void* const* d_in, const int* in_sizes, int n_in,
                              void* d_out, int out_size, void* d_ws, size_t ws_size,
                              hipStream_t stream) {
    const float* x_in    = (const float*)d_in[0];
    const int*   src     = (const int*)d_in[1];
    const int*   dst     = (const int*)d_in[2];
    const float* W_conv0 = (const float*)d_in[3];
    const float* b_conv0 = (const float*)d_in[4];
    const float* W_convs = (const float*)d_in[5];
    const float* b_convs = (const float*)d_in[6];
    const float* mW1 = (const float*)d_in[7];
    const float* mb1 = (const float*)d_in[8];
    const float* mW2 = (const float*)d_in[9];
    const float* mb2 = (const float*)d_in[10];
    const float* mW3 = (const float*)d_in[11];
    const float* mb3 = (const float*)d_in[12];
    const float* ln1_g = (const float*)d_in[13];
    const float* ln1_b = (const float*)d_in[14];
    const float* ln2_g = (const float*)d_in[15];
    const float* ln2_b = (const float*)d_in[16];
    const float* attnW = (const float*)d_in[17];
    const float* attnu = (const float*)d_in[18];
    const float* fW1 = (const float*)d_in[19];
    const float* fb1 = (const float*)d_in[20];
    const float* fW2 = (const float*)d_in[21];
    const float* fb2 = (const float*)d_in[22];
    const float* fcW = (const float*)d_in[23];
    const float* fcb = (const float*)d_in[24];
    float* out = (float*)d_out;

    // ---- workspace carve ----
    char* p = (char*)d_ws;
    auto alloc = [&](size_t bytes) { char* q = p; p += (bytes + 255) & ~(size_t)255; return q; };
    float* A = (float*)alloc((size_t)MR * DM * 4);                    // fp32 x / h stream
    unsigned short* sup16 = (unsigned short*)alloc((size_t)MR * DM * 2);
    unsigned short* act16 = (unsigned short*)alloc((size_t)MR * DM * 2);  // doubles as X16
    unsigned short* b16   = (unsigned short*)alloc((size_t)MR * DM * 2);  // LN1 output
    unsigned short* t1    = (unsigned short*)alloc((size_t)MR * 128 * 2); // also Xin16
    unsigned short* t2    = (unsigned short*)alloc((size_t)MR * 64 * 2);
    unsigned short* wt    = (unsigned short*)alloc((size_t)548864 * 2);
    float* a_score = (float*)alloc((size_t)MR * 4);
    float* rbuf    = (float*)alloc(NB * DM * 4);
    float* pm      = (float*)alloc(NB * NCH * 4);
    float* pl      = (float*)alloc(NB * NCH * 4);
    float* pv      = (float*)alloc((size_t)NB * NCH * DM * 4);
    float* colsum  = (float*)alloc(NB * DM * 4);
    int* counts   = (int*)alloc(NN * 4);
    int* row_ptr  = (int*)alloc((NN + 1) * 4);
    int* fill_pos = (int*)alloc(NN * 4);
    int* csr_src  = (int*)alloc(NE * 4);

    // bf16 transposed weights layout inside wt:
    unsigned short* Wt_conv0 = wt;                       // 256x128
    unsigned short* Wt_convs = Wt_conv0 + 32768;         // 3 x 256x256
    unsigned short* mW1t = Wt_convs + 196608;            // 128x256
    unsigned short* mW2t = mW1t + 32768;                 // 64x128
    unsigned short* mW3t = mW2t + 8192;                  // 256x64
    unsigned short* fW1t = mW3t + 16384;                 // 2 x 256x256
    unsigned short* fW2t = fW1t + 131072;                // 2 x 256x256

    const dim3 blk(256);

    // ---- CSR build (by dst) ----
    zero_i32_kernel<<<(NN + 255) / 256, blk, 0, stream>>>(counts, NN);
    hist_kernel<<<(NE + 255) / 256, blk, 0, stream>>>(dst, counts, NE);
    scan_kernel<<<1, blk, 0, stream>>>(counts, row_ptr, fill_pos, NN);
    fill_kernel<<<(NE + 255) / 256, blk, 0, stream>>>(src, dst, fill_pos, csr_src, NE);

    // ---- weight transposes (one batched launch) ----
    TDs tds;
    tds.d[0]  = {W_conv0, Wt_conv0, 128, 256};
    tds.d[1]  = {W_convs + 0 * 65536, Wt_convs + 0 * 65536, 256, 256};
    tds.d[2]  = {W_convs + 1 * 65536, Wt_convs + 1 * 65536, 256, 256};
    tds.d[3]  = {W_convs + 2 * 65536, Wt_convs + 2 * 65536, 256, 256};
    tds.d[4]  = {mW1, mW1t, 256, 128};
    tds.d[5]  = {mW2, mW2t, 128, 64};
    tds.d[6]  = {mW3, mW3t, 64, 256};
    tds.d[7]  = {fW1 + 0 * 65536, fW1t + 0 * 65536, 256, 256};
    tds.d[8]  = {fW1 + 1 * 65536, fW1t + 1 * 65536, 256, 256};
    tds.d[9]  = {fW2 + 0 * 65536, fW2t + 0 * 65536, 256, 256};
    tds.d[10] = {fW2 + 1 * 65536, fW2t + 1 * 65536, 256, 256};
    transpose_all_kernel<<<dim3(256, 11), blk, 0, stream>>>(tds);

    // ---- convert x_in to bf16 (into t1) ----
    cvt_bf16_kernel<<<(MR * 128 + 255) / 256, blk, 0, stream>>>(x_in, t1, MR * 128);

    const dim3 aggGrid(NN);

    // ---- GCN layer 0 ----
    mfma_gemm_kernel<128><<<dim3(2, MR / 64), blk, 0, stream>>>(t1, Wt_conv0, nullptr, nullptr, sup16, MR, 128, 256, 0);
    agg_kernel<<<aggGrid, blk, 0, stream>>>(sup16, row_ptr, csr_src, b_conv0, act16);
    // ---- GCN layers 1..3 ----
    for (int i = 0; i < 3; i++) {
        mfma_gemm_kernel<128><<<dim3(2, MR / 64), blk, 0, stream>>>(act16, Wt_convs + (size_t)i * 65536, nullptr, nullptr, sup16, MR, 256, 256, 0);
        agg_kernel<<<aggGrid, blk, 0, stream>>>(sup16, row_ptr, csr_src, b_convs + (size_t)i * 256, act16);
    }

    // ---- MLP ----
    mfma_gemm_kernel<128><<<dim3(1, MR / 64), blk, 0, stream>>>(act16, mW1t, mb1, nullptr, t1, MR, 256, 128, 1);
    mfma_gemm_kernel<64><<<dim3(1, MR / 64), blk, 0, stream>>>(t1, mW2t, mb2, nullptr, t2, MR, 128, 64, 1);
    mfma_gemm_kernel<128><<<dim3(2, MR / 64), blk, 0, stream>>>(t2, mW3t, mb3, A, act16, MR, 64, 256, 0);

    // ---- 2 attention/FFN blocks; x: fp32 in A, bf16 in act16 ----
    for (int i = 0; i < 2; i++) {
        const float* Wp = attnW + (size_t)i * DM * 8;
        const float* up = attnu + (size_t)i * 8;
        attn_score_kernel<<<MR / 4, blk, 0, stream>>>(act16, Wp, up, a_score);
        attn_pool_kernel<<<dim3(NCH, NB), blk, 0, stream>>>(act16, a_score, rbuf, 0, pm, pl, pv);
        attn_combine_kernel<<<NB, blk, 0, stream>>>(pm, pl, pv, rbuf);
        for (int it = 0; it < 3; it++) {
            attn_pool_kernel<<<dim3(NCH, NB), blk, 0, stream>>>(act16, a_score, rbuf, 1, pm, pl, pv);
            attn_combine_kernel<<<NB, blk, 0, stream>>>(pm, pl, pv, rbuf);
        }
        // x1 = LN(x + r) -> b16 (bf16)
        ln_bcast_kernel<<<MR / 4, blk, 0, stream>>>(A, rbuf, ln1_g + (size_t)i * DM,
                                                    ln1_b + (size_t)i * DM, b16);
        // h1 = relu(x1 @ fW1 + fb1) -> sup16
        mfma_gemm_kernel<128><<<dim3(2, MR / 64), blk, 0, stream>>>(b16, fW1t + (size_t)i * 65536,
                                                                    fb1 + (size_t)i * DM, nullptr, sup16, MR, 256, 256, 1);
        // h2 = h1 @ fW2 + fb2 -> A (fp32)
        mfma_gemm_kernel<128><<<dim3(2, MR / 64), blk, 0, stream>>>(sup16, fW2t + (size_t)i * 65536,
                                                                    fb2 + (size_t)i * DM, A, nullptr, MR, 256, 256, 0);
        // x = LN(x1 + h2) -> A (fp32) + act16 (bf16)
        ln_elem_kernel<<<MR / 4, blk, 0, stream>>>(b16, A, ln2_g + (size_t)i * DM,
                                                   ln2_b + (size_t)i * DM, A, act16);
    }

    // ---- final: mean over nodes commutes with linear layer ----
    zero_f32_kernel<<<4, blk, 0, stream>>>(colsum, NB * DM);
    colsum_kernel<<<dim3(NCH, NB), blk, 0, stream>>>(A, colsum);
    final_kernel<<<NB, dim3(64), 0, stream>>>(colsum, fcW, fcb, out);
}

// Round 3
// 924.971 us; speedup vs baseline: 2.0021x; 1.0573x over previous
//
#include <hip/hip_runtime.h>
#include <math.h>

#define NN 10000           // nodes
#define NB 4               // batch
#define NE 160000          // edges
#define DM 256             // model dim
#define MR (NB * NN)       // 40000 flattened rows
#define LN_EPS 1e-5f
#define WCHUNK 100         // node chunk (100 chunks * 100 = 10000)
#define NCH (NN / WCHUNK)  // 100

typedef __attribute__((ext_vector_type(8))) short short8;
typedef __attribute__((ext_vector_type(8))) unsigned short us8;
typedef __attribute__((ext_vector_type(4))) float floatx4;

// ---------------- helpers ----------------

__device__ inline float bf2f(unsigned short u) {
    unsigned int x = ((unsigned int)u) << 16;
    float f;
    __builtin_memcpy(&f, &x, 4);
    return f;
}

__device__ inline unsigned short f2bf(float f) {
    unsigned int x;
    __builtin_memcpy(&x, &f, 4);
    unsigned int r = x + 0x7FFFu + ((x >> 16) & 1u);
    return (unsigned short)(r >> 16);
}

__device__ inline float gelu_exact(float x) {
    return 0.5f * x * (1.0f + erff(x * 0.70710678118654752f));
}

__device__ inline float waveAllReduce(float v) {
#pragma unroll
    for (int off = 32; off > 0; off >>= 1) v += __shfl_xor(v, off, 64);
    return v;
}

// async global->LDS, 16B per lane. LDS dest must be wave-uniform + lane*16 (it is).
__device__ inline void gld16(const unsigned short* g, unsigned short* l) {
    __builtin_amdgcn_global_load_lds((const __attribute__((address_space(1))) void*)g,
                                     (__attribute__((address_space(3))) void*)l, 16, 0, 0);
}

// ---------------- utility kernels ----------------

__global__ void zero_f32_kernel(float* p, int n) {
    int i = blockIdx.x * 256 + threadIdx.x;
    if (i < n) p[i] = 0.0f;
}

__global__ void zero_i32_kernel(int* p, int n) {
    int i = blockIdx.x * 256 + threadIdx.x;
    if (i < n) p[i] = 0;
}

__global__ void cvt_bf16_kernel(const float* __restrict__ in, unsigned short* __restrict__ out, int n) {
    int i = blockIdx.x * 256 + threadIdx.x;
    if (i < n) out[i] = f2bf(in[i]);
}

// batched weight transpose+convert: Wt[n*K+k] = bf16(W[k*N+n])
struct TD { const float* src; unsigned short* dst; int K; int N; };
struct TDs { TD d[11]; };

__global__ void transpose_all_kernel(TDs tds) {
    TD t = tds.d[blockIdx.y];
    int idx = blockIdx.x * 256 + threadIdx.x;
    int total = t.K * t.N;
    if (idx < total) {
        int n = idx / t.K;
        int k = idx - n * t.K;
        t.dst[idx] = f2bf(t.src[(size_t)k * t.N + n]);
    }
}

// ---------------- CSR build ----------------

__global__ void hist_kernel(const int* __restrict__ dst, int* __restrict__ counts, int e) {
    int i = blockIdx.x * 256 + threadIdx.x;
    if (i < e) atomicAdd(&counts[dst[i]], 1);
}

__global__ __launch_bounds__(256) void scan_kernel(const int* __restrict__ counts,
                                                   int* __restrict__ row_ptr,
                                                   int* __restrict__ fill_pos, int n) {
    __shared__ int sums[256];
    int tid = threadIdx.x;
    int chunk = (n + 255) / 256;
    int s0 = tid * chunk;
    int s1 = min(n, s0 + chunk);
    int local = 0;
    for (int i = s0; i < s1; i++) local += counts[i];
    sums[tid] = local;
    __syncthreads();
    for (int off = 1; off < 256; off <<= 1) {
        int v = (tid >= off) ? sums[tid - off] : 0;
        __syncthreads();
        sums[tid] += v;
        __syncthreads();
    }
    int base = (tid == 0) ? 0 : sums[tid - 1];
    for (int i = s0; i < s1; i++) {
        row_ptr[i] = base;
        fill_pos[i] = base;
        base += counts[i];
    }
    if (tid == 255) row_ptr[n] = sums[255];
}

__global__ void fill_kernel(const int* __restrict__ src, const int* __restrict__ dst,
                            int* __restrict__ fill_pos, int* __restrict__ csr_src, int e) {
    int i = blockIdx.x * 256 + threadIdx.x;
    if (i < e) {
        int p = atomicAdd(&fill_pos[dst[i]], 1);
        csr_src[p] = src[i];
    }
}

// ---------------- MFMA GEMM ----------------
// C = act(A[MxK]bf16 @ B[KxN] + bias), B transposed bf16 as Bt[N][K].
// BM=64. Block 256 = 4 waves (2x2), wave tile 32 x (BN/2).
// Fragment-ordered LDS; staging via global_load_lds width=16.
// CM: 0 = f32 row-major, 1 = bf16 row-major, 2 = bf16 node-major [n][b*DM+col]

template <int BN, int CM>
__global__ __launch_bounds__(256) void mfma_gemm_kernel(
    const unsigned short* __restrict__ A, const unsigned short* __restrict__ Bt,
    const float* __restrict__ bias, void* __restrict__ Cp, int K, int N, int act) {
    constexpr int NBF = BN / 32;
    __shared__ unsigned short AsL[4 * 64 * 8];
    __shared__ unsigned short BsL[(BN / 16) * 64 * 8];

    const int tid = threadIdx.x;
    const int w = tid >> 6, l = tid & 63;
    const int wm = w >> 1, wn = w & 1;
    const int bm0 = blockIdx.y * 64;
    const int bn0 = blockIdx.x * BN;
    const int lm = l & 15, lq = l >> 4;

    floatx4 acc[2][NBF];
#pragma unroll
    for (int mi = 0; mi < 2; mi++)
#pragma unroll
        for (int ni = 0; ni < NBF; ni++) acc[mi][ni] = (floatx4){0.f, 0.f, 0.f, 0.f};

    const int s_ll = tid & 63;
    const int a_row = bm0 + (tid >> 6) * 16 + (s_ll & 15);
    const int s_kc = (s_ll >> 4) * 8;

    for (int k0 = 0; k0 < K; k0 += 32) {
        gld16(&A[(size_t)a_row * K + k0 + s_kc], &AsL[tid * 8]);
#pragma unroll
        for (int cc = 0; cc < BN / 64; cc++) {
            int c = tid + cc * 256;
            int rown = bn0 + (c >> 6) * 16 + (c & 15);
            int kc = k0 + ((c & 63) >> 4) * 8;
            gld16(&Bt[(size_t)rown * K + kc], &BsL[c * 8]);
        }
        __syncthreads();
        short8 af[2], bfv[NBF];
#pragma unroll
        for (int mi = 0; mi < 2; mi++) af[mi] = *(short8*)&AsL[((wm * 2 + mi) * 64 + l) * 8];
#pragma unroll
        for (int ni = 0; ni < NBF; ni++) bfv[ni] = *(short8*)&BsL[((wn * NBF + ni) * 64 + l) * 8];
#pragma unroll
        for (int mi = 0; mi < 2; mi++)
#pragma unroll
            for (int ni = 0; ni < NBF; ni++)
                acc[mi][ni] = __builtin_amdgcn_mfma_f32_16x16x32_bf16(af[mi], bfv[ni], acc[mi][ni], 0, 0, 0);
        __syncthreads();
    }

#pragma unroll
    for (int ni = 0; ni < NBF; ni++) {
        int col = bn0 + (wn * NBF + ni) * 16 + lm;
        float bv = bias ? bias[col] : 0.0f;
#pragma unroll
        for (int mi = 0; mi < 2; mi++) {
            int row0 = bm0 + (wm * 2 + mi) * 16 + lq * 4;
#pragma unroll
            for (int r = 0; r < 4; r++) {
                int row = row0 + r;
                float v = acc[mi][ni][r] + bv;
                if (act) v = fmaxf(v, 0.0f);
                if (CM == 0) {
                    ((float*)Cp)[(size_t)row * N + col] = v;
                } else if (CM == 1) {
                    ((unsigned short*)Cp)[(size_t)row * N + col] = f2bf(v);
                } else {
                    int bb = row / NN;
                    int nn = row - bb * NN;
                    ((unsigned short*)Cp)[(size_t)nn * (NB * DM) + bb * DM + col] = f2bf(v);
                }
            }
        }
    }
}

// ---------------- GCN aggregation ----------------
// sup node-major [NN][NB*DM] (2KB/node). Block = 2 nodes, 128 threads/node,
// 16B (us8) per thread covers the full 2KB node row. out row-major [MR][DM].

__global__ __launch_bounds__(256) void agg_kernel(const unsigned short* __restrict__ sup,
                                                  const int* __restrict__ row_ptr,
                                                  const int* __restrict__ csr_src,
                                                  const float* __restrict__ bias,
                                                  unsigned short* __restrict__ out) {
    int half = threadIdx.x >> 7;
    int n = blockIdx.x * 2 + half;
    int t = threadIdx.x & 127;
    int s = row_ptr[n], e = row_ptr[n + 1];
    float acc[8] = {0.f, 0.f, 0.f, 0.f, 0.f, 0.f, 0.f, 0.f};
    int j = s;
    for (; j + 4 <= e; j += 4) {
        int s0 = csr_src[j], s1 = csr_src[j + 1], s2 = csr_src[j + 2], s3 = csr_src[j + 3];
        us8 v0 = *(const us8*)&sup[(size_t)s0 * (NB * DM) + t * 8];
        us8 v1 = *(const us8*)&sup[(size_t)s1 * (NB * DM) + t * 8];
        us8 v2 = *(const us8*)&sup[(size_t)s2 * (NB * DM) + t * 8];
        us8 v3 = *(const us8*)&sup[(size_t)s3 * (NB * DM) + t * 8];
#pragma unroll
        for (int k = 0; k < 8; k++)
            acc[k] += (bf2f(v0[k]) + bf2f(v1[k])) + (bf2f(v2[k]) + bf2f(v3[k]));
    }
    for (; j < e; j++) {
        us8 v = *(const us8*)&sup[(size_t)csr_src[j] * (NB * DM) + t * 8];
#pragma unroll
        for (int k = 0; k < 8; k++) acc[k] += bf2f(v[k]);
    }
    int b = t >> 5, d0 = (t & 31) * 8;
    us8 o;
#pragma unroll
    for (int k = 0; k < 8; k++) o[k] = f2bf(gelu_exact(acc[k] + bias[d0 + k]));
    *(us8*)&out[((size_t)b * NN + n) * DM + d0] = o;
}

// ---------------- fused attention pooling ----------------
// Grid (NCH, NB). MODE 0: score = tanh(xW)u inline (first softmax pass).
// MODE 1: prologue combines previous partials into r, then score = x.r.
// Writes online-softmax partials (m, l, weighted-sum vec) per chunk.

template <int MODE>
__global__ __launch_bounds__(256) void attn_pool_kernel(const unsigned short* __restrict__ x16,
                                                        const float* __restrict__ W,
                                                        const float* __restrict__ u,
                                                        const float* __restrict__ pm_in,
                                                        const float* __restrict__ pl_in,
                                                        const float* __restrict__ pv_in,
                                                        float* __restrict__ pm_out,
                                                        float* __restrict__ pl_out,
                                                        float* __restrict__ pv_out) {
    int c = blockIdx.x, b = blockIdx.y;
    int tid = threadIdx.x, w = tid >> 6, l = tid & 63;
    __shared__ float sr[DM];
    float4 rv = {0, 0, 0, 0};
    if (MODE == 1) {
        float M = -INFINITY;
        for (int cc = 0; cc < NCH; cc++) M = fmaxf(M, pm_in[b * NCH + cc]);
        float L = 0.f, acc = 0.f;
        for (int cc = 0; cc < NCH; cc++) {
            float ee = __expf(pm_in[b * NCH + cc] - M);
            L += ee * pl_in[b * NCH + cc];
            acc += ee * pv_in[((size_t)b * NCH + cc) * DM + tid];
        }
        sr[tid] = acc / L;
        __syncthreads();
        rv = *(float4*)&sr[l * 4];
    }

    float m = -INFINITY, L = 0.0f;
    float v0 = 0.f, v1 = 0.f, v2 = 0.f, v3 = 0.f;
    int n0 = c * WCHUNK;
    for (int n = n0 + w; n < n0 + WCHUNK; n += 4) {
        ushort4 xb = *(const ushort4*)&x16[((size_t)b * NN + n) * DM + l * 4];
        float x0 = bf2f(xb.x), x1 = bf2f(xb.y), x2 = bf2f(xb.z), x3 = bf2f(xb.w);
        float s;
        if (MODE == 1) {
            s = x0 * rv.x + x1 * rv.y + x2 * rv.z + x3 * rv.w;
            s = waveAllReduce(s);
        } else {
            const float4* Wv = (const float4*)W;
            int d0 = l * 4;
            float xs[4] = {x0, x1, x2, x3};
            float t[8] = {0, 0, 0, 0, 0, 0, 0, 0};
#pragma unroll
            for (int dd = 0; dd < 4; dd++) {
                float4 w0 = Wv[(d0 + dd) * 2 + 0];
                float4 w1 = Wv[(d0 + dd) * 2 + 1];
                t[0] += xs[dd] * w0.x; t[1] += xs[dd] * w0.y; t[2] += xs[dd] * w0.z; t[3] += xs[dd] * w0.w;
                t[4] += xs[dd] * w1.x; t[5] += xs[dd] * w1.y; t[6] += xs[dd] * w1.z; t[7] += xs[dd] * w1.w;
            }
#pragma unroll
            for (int jj = 0; jj < 8; jj++) t[jj] = waveAllReduce(t[jj]);
            s = 0.f;
#pragma unroll
            for (int jj = 0; jj < 8; jj++) s += tanhf(t[jj]) * u[jj];
        }
        if (s > m) {  // wave-uniform branch
            float sc = __expf(m - s);
            L *= sc; v0 *= sc; v1 *= sc; v2 *= sc; v3 *= sc;
            m = s;
        }
        float wgt = __expf(s - m);
        L += wgt;
        v0 += wgt * x0; v1 += wgt * x1; v2 += wgt * x2; v3 += wgt * x3;
    }
    __shared__ float sm[4], sl[4];
    __shared__ float sv[4][DM];
    if (l == 0) { sm[w] = m; sl[w] = L; }
    float4 vv = {v0, v1, v2, v3};
    *(float4*)&sv[w][l * 4] = vv;
    __syncthreads();
    int d = tid;
    float M = fmaxf(fmaxf(sm[0], sm[1]), fmaxf(sm[2], sm[3]));
    float e0 = __expf(sm[0] - M), e1 = __expf(sm[1] - M);
    float e2 = __expf(sm[2] - M), e3 = __expf(sm[3] - M);
    float Lt = e0 * sl[0] + e1 * sl[1] + e2 * sl[2] + e3 * sl[3];
    float vd = e0 * sv[0][d] + e1 * sv[1][d] + e2 * sv[2][d] + e3 * sv[3][d];
    pv_out[((size_t)b * NCH + c) * DM + d] = vd;
    if (d == 0) {
        pm_out[b * NCH + c] = M;
        pl_out[b * NCH + c] = Lt;
    }
}

__global__ __launch_bounds__(256) void attn_combine_kernel(const float* __restrict__ pm,
                                                           const float* __restrict__ pl,
                                                           const float* __restrict__ pv,
                                                           float* __restrict__ r) {
    int b = blockIdx.x, d = threadIdx.x;
    float M = -INFINITY;
    for (int c = 0; c < NCH; c++) M = fmaxf(M, pm[b * NCH + c]);
    float L = 0.0f, acc = 0.0f;
    for (int c = 0; c < NCH; c++) {
        float e = __expf(pm[b * NCH + c] - M);
        L += e * pl[b * NCH + c];
        acc += e * pv[((size_t)b * NCH + c) * DM + d];
    }
    r[b * DM + d] = acc / L;
}

// ---------------- LayerNorm ----------------

// out16 = LN(x16 + r[b])
__global__ __launch_bounds__(256) void ln_bcast_kernel(const unsigned short* __restrict__ x16,
                                                       const float* __restrict__ r,
                                                       const float* __restrict__ g,
                                                       const float* __restrict__ bt,
                                                       unsigned short* __restrict__ out16) {
    int l = threadIdx.x & 63, w = threadIdx.x >> 6;
    int row = blockIdx.x * 4 + w;
    int b = row / NN;
    ushort4 xb = *(const ushort4*)&x16[(size_t)row * DM + l * 4];
    float4 rv = *(const float4*)(r + (size_t)b * DM + l * 4);
    float4 y;
    y.x = bf2f(xb.x) + rv.x; y.y = bf2f(xb.y) + rv.y;
    y.z = bf2f(xb.z) + rv.z; y.w = bf2f(xb.w) + rv.w;
    float s = y.x + y.y + y.z + y.w;
    float sq = y.x * y.x + y.y * y.y + y.z * y.z + y.w * y.w;
    s = waveAllReduce(s);
    sq = waveAllReduce(sq);
    float mean = s * (1.0f / 256.0f);
    float var = sq * (1.0f / 256.0f) - mean * mean;
    float rstd = rsqrtf(var + LN_EPS);
    float4 gv = *(const float4*)(g + l * 4);
    float4 bv = *(const float4*)(bt + l * 4);
    ushort4 o;
    o.x = f2bf((y.x - mean) * rstd * gv.x + bv.x);
    o.y = f2bf((y.y - mean) * rstd * gv.y + bv.y);
    o.z = f2bf((y.z - mean) * rstd * gv.z + bv.z);
    o.w = f2bf((y.w - mean) * rstd * gv.w + bv.w);
    *(ushort4*)&out16[(size_t)row * DM + l * 4] = o;
}

// out16 = LN(x16 + h_f32)
__global__ __launch_bounds__(256) void ln_elem_kernel(const unsigned short* __restrict__ x16,
                                                      const float* __restrict__ h,
                                                      const float* __restrict__ g,
                                                      const float* __restrict__ bt,
                                                      unsigned short* __restrict__ out16) {
    int l = threadIdx.x & 63, w = threadIdx.x >> 6;
    int row = blockIdx.x * 4 + w;
    ushort4 xb = *(const ushort4*)&x16[(size_t)row * DM + l * 4];
    float4 hv = *(const float4*)(h + (size_t)row * DM + l * 4);
    float4 y;
    y.x = bf2f(xb.x) + hv.x; y.y = bf2f(xb.y) + hv.y;
    y.z = bf2f(xb.z) + hv.z; y.w = bf2f(xb.w) + hv.w;
    float s = y.x + y.y + y.z + y.w;
    float sq = y.x * y.x + y.y * y.y + y.z * y.z + y.w * y.w;
    s = waveAllReduce(s);
    sq = waveAllReduce(sq);
    float mean = s * (1.0f / 256.0f);
    float var = sq * (1.0f / 256.0f) - mean * mean;
    float rstd = rsqrtf(var + LN_EPS);
    float4 gv = *(const float4*)(g + l * 4);
    float4 bv = *(const float4*)(bt + l * 4);
    ushort4 o;
    o.x = f2bf((y.x - mean) * rstd * gv.x + bv.x);
    o.y = f2bf((y.y - mean) * rstd * gv.y + bv.y);
    o.z = f2bf((y.z - mean) * rstd * gv.z + bv.z);
    o.w = f2bf((y.w - mean) * rstd * gv.w + bv.w);
    *(ushort4*)&out16[(size_t)row * DM + l * 4] = o;
}

// ---------------- final projection ----------------

__global__ __launch_bounds__(256) void colsum_kernel(const unsigned short* __restrict__ x16,
                                                     float* __restrict__ cs) {
    int b = blockIdx.y, c = blockIdx.x, d = threadIdx.x;
    int n0 = c * WCHUNK, n1 = n0 + WCHUNK;
    float acc = 0.0f;
    for (int n = n0; n < n1; n++) acc += bf2f(x16[((size_t)b * NN + n) * DM + d]);
    atomicAdd(&cs[b * DM + d], acc);
}

__global__ __launch_bounds__(64) void final_kernel(const float* __restrict__ cs,
                                                   const float* __restrict__ fcW,
                                                   const float* __restrict__ fcb,
                                                   float* __restrict__ out) {
    int b = blockIdx.x;
    int o = threadIdx.x;
    if (o < 10) {
        float acc = 0.0f;
        for (int d = 0; d < DM; d++) acc += cs[b * DM + d] * fcW[d * 10 + o];
        out[b * 10 + o] = acc * (1.0f / NN) + fcb[o];
    }
}

// ---------------- launch ----------------

extern "C" void kernel_launch(void* const* d_in, const int* in_sizes, int n_in,
                              void* d_out, int out_size, void* d_ws, size_t ws_size,
                              hipStream_t stream) {
    const float* x_in    = (const float*)d_in[0];
    const int*   src     = (const int*)d_in[1];
    const int*   dst     = (const int*)d_in[2];
    const float* W_conv0 = (const float*)d_in[3];
    const float* b_conv0 = (const float*)d_in[4];
    const float* W_convs = (const float*)d_in[5];
    const float* b_convs = (const float*)d_in[6];
    const float* mW1 = (const float*)d_in[7];
    const float* mb1 = (const float*)d_in[8];
    const float* mW2 = (const float*)d_in[9];
    const float* mb2 = (const float*)d_in[10];
    const float* mW3 = (const float*)d_in[11];
    const float* mb3 = (const float*)d_in[12];
    const float* ln1_g = (const float*)d_in[13];
    const float* ln1_b = (const float*)d_in[14];
    const float* ln2_g = (const float*)d_in[15];
    const float* ln2_b = (const float*)d_in[16];
    const float* attnW = (const float*)d_in[17];
    const float* attnu = (const float*)d_in[18];
    const float* fW1 = (const float*)d_in[19];
    const float* fb1 = (const float*)d_in[20];
    const float* fW2 = (const float*)d_in[21];
    const float* fb2 = (const float*)d_in[22];
    const float* fcW = (const float*)d_in[23];
    const float* fcb = (const float*)d_in[24];
    float* out = (float*)d_out;

    // ---- workspace carve ----
    char* p = (char*)d_ws;
    auto alloc = [&](size_t bytes) { char* q = p; p += (bytes + 255) & ~(size_t)255; return q; };
    float* A = (float*)alloc((size_t)MR * DM * 4);                        // fp32 h stream
    unsigned short* sup16 = (unsigned short*)alloc((size_t)MR * DM * 2);  // node-major sup / h1
    unsigned short* act16 = (unsigned short*)alloc((size_t)MR * DM * 2);  // x bf16
    unsigned short* b16   = (unsigned short*)alloc((size_t)MR * DM * 2);  // LN1 output
    unsigned short* t1    = (unsigned short*)alloc((size_t)MR * 128 * 2);
    unsigned short* t2    = (unsigned short*)alloc((size_t)MR * 64 * 2);
    unsigned short* wt    = (unsigned short*)alloc((size_t)548864 * 2);
    float* rbuf = (float*)alloc(NB * DM * 4);
    float* pm0  = (float*)alloc(NB * NCH * 4);
    float* pl0  = (float*)alloc(NB * NCH * 4);
    float* pv0  = (float*)alloc((size_t)NB * NCH * DM * 4);
    float* pm1  = (float*)alloc(NB * NCH * 4);
    float* pl1  = (float*)alloc(NB * NCH * 4);
    float* pv1  = (float*)alloc((size_t)NB * NCH * DM * 4);
    float* colsum = (float*)alloc(NB * DM * 4);
    int* counts   = (int*)alloc(NN * 4);
    int* row_ptr  = (int*)alloc((NN + 1) * 4);
    int* fill_pos = (int*)alloc(NN * 4);
    int* csr_src  = (int*)alloc(NE * 4);

    unsigned short* Wt_conv0 = wt;                       // 256x128
    unsigned short* Wt_convs = Wt_conv0 + 32768;         // 3 x 256x256
    unsigned short* mW1t = Wt_convs + 196608;            // 128x256
    unsigned short* mW2t = mW1t + 32768;                 // 64x128
    unsigned short* mW3t = mW2t + 8192;                  // 256x64
    unsigned short* fW1t = mW3t + 16384;                 // 2 x 256x256
    unsigned short* fW2t = fW1t + 131072;                // 2 x 256x256

    const dim3 blk(256);

    // ---- CSR build (by dst) ----
    zero_i32_kernel<<<(NN + 255) / 256, blk, 0, stream>>>(counts, NN);
    hist_kernel<<<(NE + 255) / 256, blk, 0, stream>>>(dst, counts, NE);
    scan_kernel<<<1, blk, 0, stream>>>(counts, row_ptr, fill_pos, NN);
    fill_kernel<<<(NE + 255) / 256, blk, 0, stream>>>(src, dst, fill_pos, csr_src, NE);

    // ---- weight transposes ----
    TDs tds;
    tds.d[0]  = {W_conv0, Wt_conv0, 128, 256};
    tds.d[1]  = {W_convs + 0 * 65536, Wt_convs + 0 * 65536, 256, 256};
    tds.d[2]  = {W_convs + 1 * 65536, Wt_convs + 1 * 65536, 256, 256};
    tds.d[3]  = {W_convs + 2 * 65536, Wt_convs + 2 * 65536, 256, 256};
    tds.d[4]  = {mW1, mW1t, 256, 128};
    tds.d[5]  = {mW2, mW2t, 128, 64};
    tds.d[6]  = {mW3, mW3t, 64, 256};
    tds.d[7]  = {fW1 + 0 * 65536, fW1t + 0 * 65536, 256, 256};
    tds.d[8]  = {fW1 + 1 * 65536, fW1t + 1 * 65536, 256, 256};
    tds.d[9]  = {fW2 + 0 * 65536, fW2t + 0 * 65536, 256, 256};
    tds.d[10] = {fW2 + 1 * 65536, fW2t + 1 * 65536, 256, 256};
    transpose_all_kernel<<<dim3(256, 11), blk, 0, stream>>>(tds);

    cvt_bf16_kernel<<<(MR * 128 + 255) / 256, blk, 0, stream>>>(x_in, t1, MR * 128);

    // ---- GCN layers (GEMM writes node-major sup16; agg emits row-major bf16) ----
    mfma_gemm_kernel<128, 2><<<dim3(2, MR / 64), blk, 0, stream>>>(t1, Wt_conv0, nullptr, sup16, 128, 256, 0);
    agg_kernel<<<NN / 2, blk, 0, stream>>>(sup16, row_ptr, csr_src, b_conv0, act16);
    for (int i = 0; i < 3; i++) {
        mfma_gemm_kernel<128, 2><<<dim3(2, MR / 64), blk, 0, stream>>>(act16, Wt_convs + (size_t)i * 65536, nullptr, sup16, 256, 256, 0);
        agg_kernel<<<NN / 2, blk, 0, stream>>>(sup16, row_ptr, csr_src, b_convs + (size_t)i * 256, act16);
    }

    // ---- MLP ----
    mfma_gemm_kernel<128, 1><<<dim3(1, MR / 64), blk, 0, stream>>>(act16, mW1t, mb1, t1, 256, 128, 1);
    mfma_gemm_kernel<64, 1><<<dim3(1, MR / 64), blk, 0, stream>>>(t1, mW2t, mb2, t2, 128, 64, 1);
    mfma_gemm_kernel<128, 1><<<dim3(2, MR / 64), blk, 0, stream>>>(t2, mW3t, mb3, act16, 64, 256, 0);

    // ---- 2 attention/FFN blocks; x bf16 in act16 ----
    const dim3 poolGrid(NCH, NB);
    for (int i = 0; i < 2; i++) {
        const float* Wp = attnW + (size_t)i * DM * 8;
        const float* up = attnu + (size_t)i * 8;
        attn_pool_kernel<0><<<poolGrid, blk, 0, stream>>>(act16, Wp, up, nullptr, nullptr, nullptr, pm0, pl0, pv0);
        attn_pool_kernel<1><<<poolGrid, blk, 0, stream>>>(act16, nullptr, nullptr, pm0, pl0, pv0, pm1, pl1, pv1);
        attn_pool_kernel<1><<<poolGrid, blk, 0, stream>>>(act16, nullptr, nullptr, pm1, pl1, pv1, pm0, pl0, pv0);
        attn_pool_kernel<1><<<poolGrid, blk, 0, stream>>>(act16, nullptr, nullptr, pm0, pl0, pv0, pm1, pl1, pv1);
        attn_combine_kernel<<<NB, blk, 0, stream>>>(pm1, pl1, pv1, rbuf);
        // x1 = LN(x + r) -> b16
        ln_bcast_kernel<<<MR / 4, blk, 0, stream>>>(act16, rbuf, ln1_g + (size_t)i * DM,
                                                    ln1_b + (size_t)i * DM, b16);
        // h1 = relu(x1 @ fW1 + fb1) -> sup16 (row-major bf16)
        mfma_gemm_kernel<128, 1><<<dim3(2, MR / 64), blk, 0, stream>>>(b16, fW1t + (size_t)i * 65536,
                                                                       fb1 + (size_t)i * DM, sup16, 256, 256, 1);
        // h2 = h1 @ fW2 + fb2 -> A (fp32)
        mfma_gemm_kernel<128, 0><<<dim3(2, MR / 64), blk, 0, stream>>>(sup16, fW2t + (size_t)i * 65536,
                                                                       fb2 + (size_t)i * DM, A, 256, 256, 0);
        // x = LN(x1 + h2) -> act16
        ln_elem_kernel<<<MR / 4, blk, 0, stream>>>(b16, A, ln2_g + (size_t)i * DM,
                                                   ln2_b + (size_t)i * DM, act16);
    }

    // ---- final: mean over nodes commutes with the linear layer ----
    zero_f32_kernel<<<4, blk, 0, stream>>>(colsum, NB * DM);
    colsum_kernel<<<poolGrid, blk, 0, stream>>>(act16, colsum);
    final_kernel<<<NB, dim3(64), 0, stream>>>(colsum, fcW, fcb, out);
}

// Round 4
// 879.312 us; speedup vs baseline: 2.1061x; 1.0519x over previous
//
#include <hip/hip_runtime.h>
#include <math.h>

#define NN 10000           // nodes
#define NB 4               // batch
#define NE 160000          // edges
#define DM 256             // model dim
#define MR (NB * NN)       // 40000 flattened rows
#define LN_EPS 1e-5f
#define WCHUNK 100         // node chunk (100 chunks * 100 = 10000)
#define NCH (NN / WCHUNK)  // 100

typedef __attribute__((ext_vector_type(8))) short short8;
typedef __attribute__((ext_vector_type(8))) unsigned short us8;
typedef __attribute__((ext_vector_type(4))) float floatx4;

// ---------------- helpers ----------------

__device__ inline float bf2f(unsigned short u) {
    unsigned int x = ((unsigned int)u) << 16;
    float f;
    __builtin_memcpy(&f, &x, 4);
    return f;
}

__device__ inline unsigned short f2bf(float f) {
    unsigned int x;
    __builtin_memcpy(&x, &f, 4);
    unsigned int r = x + 0x7FFFu + ((x >> 16) & 1u);
    return (unsigned short)(r >> 16);
}

__device__ inline float gelu_exact(float x) {
    return 0.5f * x * (1.0f + erff(x * 0.70710678118654752f));
}

__device__ inline float waveAllReduce(float v) {
#pragma unroll
    for (int off = 32; off > 0; off >>= 1) v += __shfl_xor(v, off, 64);
    return v;
}

// async global->LDS, 16B per lane. LDS dest must be wave-uniform + lane*16 (it is).
__device__ inline void gld16(const unsigned short* g, unsigned short* l) {
    __builtin_amdgcn_global_load_lds((const __attribute__((address_space(1))) void*)g,
                                     (__attribute__((address_space(3))) void*)l, 16, 0, 0);
}

// ---------------- utility kernels ----------------

__global__ void zero_f32_kernel(float* p, int n) {
    int i = blockIdx.x * 256 + threadIdx.x;
    if (i < n) p[i] = 0.0f;
}

__global__ void zero_i32_kernel(int* p, int n) {
    int i = blockIdx.x * 256 + threadIdx.x;
    if (i < n) p[i] = 0;
}

__global__ void cvt_bf16_kernel(const float* __restrict__ in, unsigned short* __restrict__ out, int n) {
    int i = blockIdx.x * 256 + threadIdx.x;
    if (i < n) out[i] = f2bf(in[i]);
}

// batched weight transpose+convert: Wt[n*K+k] = bf16(W[k*N+n])
struct TD { const float* src; unsigned short* dst; int K; int N; };
struct TDs { TD d[11]; };

__global__ void transpose_all_kernel(TDs tds) {
    TD t = tds.d[blockIdx.y];
    int idx = blockIdx.x * 256 + threadIdx.x;
    int total = t.K * t.N;
    if (idx < total) {
        int n = idx / t.K;
        int k = idx - n * t.K;
        t.dst[idx] = f2bf(t.src[(size_t)k * t.N + n]);
    }
}

// ---------------- CSR build ----------------

__global__ void hist_kernel(const int* __restrict__ dst, int* __restrict__ counts, int e) {
    int i = blockIdx.x * 256 + threadIdx.x;
    if (i < e) atomicAdd(&counts[dst[i]], 1);
}

__global__ __launch_bounds__(256) void scan_kernel(const int* __restrict__ counts,
                                                   int* __restrict__ row_ptr,
                                                   int* __restrict__ fill_pos, int n) {
    __shared__ int sums[256];
    int tid = threadIdx.x;
    int chunk = (n + 255) / 256;
    int s0 = tid * chunk;
    int s1 = min(n, s0 + chunk);
    int local = 0;
    for (int i = s0; i < s1; i++) local += counts[i];
    sums[tid] = local;
    __syncthreads();
    for (int off = 1; off < 256; off <<= 1) {
        int v = (tid >= off) ? sums[tid - off] : 0;
        __syncthreads();
        sums[tid] += v;
        __syncthreads();
    }
    int base = (tid == 0) ? 0 : sums[tid - 1];
    for (int i = s0; i < s1; i++) {
        row_ptr[i] = base;
        fill_pos[i] = base;
        base += counts[i];
    }
    if (tid == 255) row_ptr[n] = sums[255];
}

__global__ void fill_kernel(const int* __restrict__ src, const int* __restrict__ dst,
                            int* __restrict__ fill_pos, int* __restrict__ csr_src, int e) {
    int i = blockIdx.x * 256 + threadIdx.x;
    if (i < e) {
        int p = atomicAdd(&fill_pos[dst[i]], 1);
        csr_src[p] = src[i];
    }
}

// ---------------- MFMA GEMM ----------------
// C = act(A[MxK]bf16 @ B[KxN] + bias), B transposed bf16 as Bt[N][K].
// BM=64. Block 256 = 4 waves (2x2), wave tile 32 x (BN/2).
// Fragment-ordered LDS; staging via global_load_lds width=16.
// CM: 0 = f32 row-major, 1 = bf16 row-major, 2 = bf16 node-major [n][b*DM+col]

template <int BN, int CM>
__global__ __launch_bounds__(256) void mfma_gemm_kernel(
    const unsigned short* __restrict__ A, const unsigned short* __restrict__ Bt,
    const float* __restrict__ bias, void* __restrict__ Cp, int K, int N, int act) {
    constexpr int NBF = BN / 32;
    __shared__ unsigned short AsL[4 * 64 * 8];
    __shared__ unsigned short BsL[(BN / 16) * 64 * 8];

    const int tid = threadIdx.x;
    const int w = tid >> 6, l = tid & 63;
    const int wm = w >> 1, wn = w & 1;
    const int bm0 = blockIdx.y * 64;
    const int bn0 = blockIdx.x * BN;
    const int lm = l & 15, lq = l >> 4;

    floatx4 acc[2][NBF];
#pragma unroll
    for (int mi = 0; mi < 2; mi++)
#pragma unroll
        for (int ni = 0; ni < NBF; ni++) acc[mi][ni] = (floatx4){0.f, 0.f, 0.f, 0.f};

    const int s_ll = tid & 63;
    const int a_row = bm0 + (tid >> 6) * 16 + (s_ll & 15);
    const int s_kc = (s_ll >> 4) * 8;

    for (int k0 = 0; k0 < K; k0 += 32) {
        gld16(&A[(size_t)a_row * K + k0 + s_kc], &AsL[tid * 8]);
#pragma unroll
        for (int cc = 0; cc < BN / 64; cc++) {
            int c = tid + cc * 256;
            int rown = bn0 + (c >> 6) * 16 + (c & 15);
            int kc = k0 + ((c & 63) >> 4) * 8;
            gld16(&Bt[(size_t)rown * K + kc], &BsL[c * 8]);
        }
        __syncthreads();
        short8 af[2], bfv[NBF];
#pragma unroll
        for (int mi = 0; mi < 2; mi++) af[mi] = *(short8*)&AsL[((wm * 2 + mi) * 64 + l) * 8];
#pragma unroll
        for (int ni = 0; ni < NBF; ni++) bfv[ni] = *(short8*)&BsL[((wn * NBF + ni) * 64 + l) * 8];
#pragma unroll
        for (int mi = 0; mi < 2; mi++)
#pragma unroll
            for (int ni = 0; ni < NBF; ni++)
                acc[mi][ni] = __builtin_amdgcn_mfma_f32_16x16x32_bf16(af[mi], bfv[ni], acc[mi][ni], 0, 0, 0);
        __syncthreads();
    }

#pragma unroll
    for (int ni = 0; ni < NBF; ni++) {
        int col = bn0 + (wn * NBF + ni) * 16 + lm;
        float bv = bias ? bias[col] : 0.0f;
#pragma unroll
        for (int mi = 0; mi < 2; mi++) {
            int row0 = bm0 + (wm * 2 + mi) * 16 + lq * 4;
#pragma unroll
            for (int r = 0; r < 4; r++) {
                int row = row0 + r;
                float v = acc[mi][ni][r] + bv;
                if (act) v = fmaxf(v, 0.0f);
                if (CM == 0) {
                    ((float*)Cp)[(size_t)row * N + col] = v;
                } else if (CM == 1) {
                    ((unsigned short*)Cp)[(size_t)row * N + col] = f2bf(v);
                } else {
                    int bb = row / NN;
                    int nn = row - bb * NN;
                    ((unsigned short*)Cp)[(size_t)nn * (NB * DM) + bb * DM + col] = f2bf(v);
                }
            }
        }
    }
}

// ---------------- GCN aggregation ----------------
// sup node-major [NN][NB*DM] (2KB/node). Block = 2 nodes, 128 threads/node,
// 16B (us8) per thread covers the full 2KB node row. out row-major [MR][DM].

__global__ __launch_bounds__(256) void agg_kernel(const unsigned short* __restrict__ sup,
                                                  const int* __restrict__ row_ptr,
                                                  const int* __restrict__ csr_src,
                                                  const float* __restrict__ bias,
                                                  unsigned short* __restrict__ out) {
    int half = threadIdx.x >> 7;
    int n = blockIdx.x * 2 + half;
    int t = threadIdx.x & 127;
    int s = row_ptr[n], e = row_ptr[n + 1];
    float acc[8] = {0.f, 0.f, 0.f, 0.f, 0.f, 0.f, 0.f, 0.f};
    int j = s;
    for (; j + 4 <= e; j += 4) {
        int s0 = csr_src[j], s1 = csr_src[j + 1], s2 = csr_src[j + 2], s3 = csr_src[j + 3];
        us8 v0 = *(const us8*)&sup[(size_t)s0 * (NB * DM) + t * 8];
        us8 v1 = *(const us8*)&sup[(size_t)s1 * (NB * DM) + t * 8];
        us8 v2 = *(const us8*)&sup[(size_t)s2 * (NB * DM) + t * 8];
        us8 v3 = *(const us8*)&sup[(size_t)s3 * (NB * DM) + t * 8];
#pragma unroll
        for (int k = 0; k < 8; k++)
            acc[k] += (bf2f(v0[k]) + bf2f(v1[k])) + (bf2f(v2[k]) + bf2f(v3[k]));
    }
    for (; j < e; j++) {
        us8 v = *(const us8*)&sup[(size_t)csr_src[j] * (NB * DM) + t * 8];
#pragma unroll
        for (int k = 0; k < 8; k++) acc[k] += bf2f(v[k]);
    }
    int b = t >> 5, d0 = (t & 31) * 8;
    us8 o;
#pragma unroll
    for (int k = 0; k < 8; k++) o[k] = f2bf(gelu_exact(acc[k] + bias[d0 + k]));
    *(us8*)&out[((size_t)b * NN + n) * DM + d0] = o;
}

// ---------------- attention pooling ----------------

// s[row] = sum_j tanh( (x_row @ W)[j] ) * u[j] ; W: 256x8, u: 8 ; x bf16
__global__ __launch_bounds__(256) void attn_score_kernel(const unsigned short* __restrict__ x16,
                                                         const float* __restrict__ W,
                                                         const float* __restrict__ u,
                                                         float* __restrict__ s) {
    int l = threadIdx.x & 63, w = threadIdx.x >> 6;
    int idx = blockIdx.x * 4 + w;
    ushort4 xb = *(const ushort4*)&x16[(size_t)idx * DM + l * 4];
    float xs[4] = {bf2f(xb.x), bf2f(xb.y), bf2f(xb.z), bf2f(xb.w)};
    const float4* Wv = (const float4*)W;
    int d0 = l * 4;
    float t[8] = {0, 0, 0, 0, 0, 0, 0, 0};
#pragma unroll
    for (int dd = 0; dd < 4; dd++) {
        float4 w0 = Wv[(d0 + dd) * 2 + 0];
        float4 w1 = Wv[(d0 + dd) * 2 + 1];
        t[0] += xs[dd] * w0.x; t[1] += xs[dd] * w0.y; t[2] += xs[dd] * w0.z; t[3] += xs[dd] * w0.w;
        t[4] += xs[dd] * w1.x; t[5] += xs[dd] * w1.y; t[6] += xs[dd] * w1.z; t[7] += xs[dd] * w1.w;
    }
#pragma unroll
    for (int j = 0; j < 8; j++) t[j] = waveAllReduce(t[j]);
    if (l == 0) {
        float acc = 0.0f;
#pragma unroll
        for (int j = 0; j < 8; j++) acc += tanhf(t[j]) * u[j];
        s[idx] = acc;
    }
}

// s[row] = x_row . r[b]  (wave per row)
__global__ __launch_bounds__(256) void dot_kernel(const unsigned short* __restrict__ x16,
                                                  const float* __restrict__ r,
                                                  float* __restrict__ s) {
    int l = threadIdx.x & 63, w = threadIdx.x >> 6;
    int idx = blockIdx.x * 4 + w;
    int b = idx / NN;
    ushort4 xb = *(const ushort4*)&x16[(size_t)idx * DM + l * 4];
    float4 rv = *(const float4*)&r[b * DM + l * 4];
    float acc = bf2f(xb.x) * rv.x + bf2f(xb.y) * rv.y + bf2f(xb.z) * rv.z + bf2f(xb.w) * rv.w;
    acc = waveAllReduce(acc);
    if (l == 0) s[idx] = acc;
}

// online-softmax partial weighted sum over a chunk; s precomputed (wave-uniform).
__global__ __launch_bounds__(256) void attn_pool_kernel(const unsigned short* __restrict__ x16,
                                                        const float* __restrict__ sarr,
                                                        float* __restrict__ pm,
                                                        float* __restrict__ pl,
                                                        float* __restrict__ pv) {
    int c = blockIdx.x, b = blockIdx.y;
    int tid = threadIdx.x, w = tid >> 6, l = tid & 63;
    int n0 = c * WCHUNK;
    float m = -INFINITY, L = 0.0f;
    float v0 = 0.f, v1 = 0.f, v2 = 0.f, v3 = 0.f;
    for (int n = n0 + w; n < n0 + WCHUNK; n += 4) {
        float s = sarr[b * NN + n];  // wave-uniform scalar
        ushort4 xb = *(const ushort4*)&x16[((size_t)b * NN + n) * DM + l * 4];
        float x0 = bf2f(xb.x), x1 = bf2f(xb.y), x2 = bf2f(xb.z), x3 = bf2f(xb.w);
        if (s > m) {  // wave-uniform branch
            float sc = __expf(m - s);
            L *= sc; v0 *= sc; v1 *= sc; v2 *= sc; v3 *= sc;
            m = s;
        }
        float wgt = __expf(s - m);
        L += wgt;
        v0 += wgt * x0; v1 += wgt * x1; v2 += wgt * x2; v3 += wgt * x3;
    }
    __shared__ float sm[4], sl[4];
    __shared__ float sv[4][DM];
    if (l == 0) { sm[w] = m; sl[w] = L; }
    float4 vv = {v0, v1, v2, v3};
    *(float4*)&sv[w][l * 4] = vv;
    __syncthreads();
    int d = tid;
    float M = fmaxf(fmaxf(sm[0], sm[1]), fmaxf(sm[2], sm[3]));
    float e0 = __expf(sm[0] - M), e1 = __expf(sm[1] - M);
    float e2 = __expf(sm[2] - M), e3 = __expf(sm[3] - M);
    float Lt = e0 * sl[0] + e1 * sl[1] + e2 * sl[2] + e3 * sl[3];
    float vd = e0 * sv[0][d] + e1 * sv[1][d] + e2 * sv[2][d] + e3 * sv[3][d];
    pv[((size_t)b * NCH + c) * DM + d] = vd;
    if (d == 0) {
        pm[b * NCH + c] = M;
        pl[b * NCH + c] = Lt;
    }
}

// one block per batch; parallel reductions over NCH chunks.
__global__ __launch_bounds__(256) void attn_combine_kernel(const float* __restrict__ pm,
                                                           const float* __restrict__ pl,
                                                           const float* __restrict__ pv,
                                                           float* __restrict__ r) {
    int b = blockIdx.x, tid = threadIdx.x;
    __shared__ float red[256];
    __shared__ float se[NCH];
    float mv = (tid < NCH) ? pm[b * NCH + tid] : -INFINITY;
    red[tid] = mv;
    __syncthreads();
    for (int off = 128; off > 0; off >>= 1) {
        if (tid < off) red[tid] = fmaxf(red[tid], red[tid + off]);
        __syncthreads();
    }
    float M = red[0];
    __syncthreads();
    float e = (tid < NCH) ? __expf(mv - M) : 0.0f;
    if (tid < NCH) se[tid] = e;
    red[tid] = (tid < NCH) ? e * pl[b * NCH + tid] : 0.0f;
    __syncthreads();
    for (int off = 128; off > 0; off >>= 1) {
        if (tid < off) red[tid] += red[tid + off];
        __syncthreads();
    }
    float L = red[0];
    __syncthreads();
    float acc = 0.0f;
    for (int c = 0; c < NCH; c++) acc += se[c] * pv[((size_t)b * NCH + c) * DM + tid];
    r[b * DM + tid] = acc / L;
}

// ---------------- LayerNorm ----------------

// out16 = LN(x16 + r[b])
__global__ __launch_bounds__(256) void ln_bcast_kernel(const unsigned short* __restrict__ x16,
                                                       const float* __restrict__ r,
                                                       const float* __restrict__ g,
                                                       const float* __restrict__ bt,
                                                       unsigned short* __restrict__ out16) {
    int l = threadIdx.x & 63, w = threadIdx.x >> 6;
    int row = blockIdx.x * 4 + w;
    int b = row / NN;
    ushort4 xb = *(const ushort4*)&x16[(size_t)row * DM + l * 4];
    float4 rv = *(const float4*)(r + (size_t)b * DM + l * 4);
    float4 y;
    y.x = bf2f(xb.x) + rv.x; y.y = bf2f(xb.y) + rv.y;
    y.z = bf2f(xb.z) + rv.z; y.w = bf2f(xb.w) + rv.w;
    float s = y.x + y.y + y.z + y.w;
    float sq = y.x * y.x + y.y * y.y + y.z * y.z + y.w * y.w;
    s = waveAllReduce(s);
    sq = waveAllReduce(sq);
    float mean = s * (1.0f / 256.0f);
    float var = sq * (1.0f / 256.0f) - mean * mean;
    float rstd = rsqrtf(var + LN_EPS);
    float4 gv = *(const float4*)(g + l * 4);
    float4 bv = *(const float4*)(bt + l * 4);
    ushort4 o;
    o.x = f2bf((y.x - mean) * rstd * gv.x + bv.x);
    o.y = f2bf((y.y - mean) * rstd * gv.y + bv.y);
    o.z = f2bf((y.z - mean) * rstd * gv.z + bv.z);
    o.w = f2bf((y.w - mean) * rstd * gv.w + bv.w);
    *(ushort4*)&out16[(size_t)row * DM + l * 4] = o;
}

// out16 = LN(x16 + h_f32)
__global__ __launch_bounds__(256) void ln_elem_kernel(const unsigned short* __restrict__ x16,
                                                      const float* __restrict__ h,
                                                      const float* __restrict__ g,
                                                      const float* __restrict__ bt,
                                                      unsigned short* __restrict__ out16) {
    int l = threadIdx.x & 63, w = threadIdx.x >> 6;
    int row = blockIdx.x * 4 + w;
    ushort4 xb = *(const ushort4*)&x16[(size_t)row * DM + l * 4];
    float4 hv = *(const float4*)(h + (size_t)row * DM + l * 4);
    float4 y;
    y.x = bf2f(xb.x) + hv.x; y.y = bf2f(xb.y) + hv.y;
    y.z = bf2f(xb.z) + hv.z; y.w = bf2f(xb.w) + hv.w;
    float s = y.x + y.y + y.z + y.w;
    float sq = y.x * y.x + y.y * y.y + y.z * y.z + y.w * y.w;
    s = waveAllReduce(s);
    sq = waveAllReduce(sq);
    float mean = s * (1.0f / 256.0f);
    float var = sq * (1.0f / 256.0f) - mean * mean;
    float rstd = rsqrtf(var + LN_EPS);
    float4 gv = *(const float4*)(g + l * 4);
    float4 bv = *(const float4*)(bt + l * 4);
    ushort4 o;
    o.x = f2bf((y.x - mean) * rstd * gv.x + bv.x);
    o.y = f2bf((y.y - mean) * rstd * gv.y + bv.y);
    o.z = f2bf((y.z - mean) * rstd * gv.z + bv.z);
    o.w = f2bf((y.w - mean) * rstd * gv.w + bv.w);
    *(ushort4*)&out16[(size_t)row * DM + l * 4] = o;
}

// ---------------- final projection ----------------

__global__ __launch_bounds__(256) void colsum_kernel(const unsigned short* __restrict__ x16,
                                                     float* __restrict__ cs) {
    int b = blockIdx.y, c = blockIdx.x, d = threadIdx.x;
    int n0 = c * WCHUNK, n1 = n0 + WCHUNK;
    float acc = 0.0f;
    for (int n = n0; n < n1; n++) acc += bf2f(x16[((size_t)b * NN + n) * DM + d]);
    atomicAdd(&cs[b * DM + d], acc);
}

__global__ __launch_bounds__(64) void final_kernel(const float* __restrict__ cs,
                                                   const float* __restrict__ fcW,
                                                   const float* __restrict__ fcb,
                                                   float* __restrict__ out) {
    int b = blockIdx.x;
    int o = threadIdx.x;
    if (o < 10) {
        float acc = 0.0f;
        for (int d = 0; d < DM; d++) acc += cs[b * DM + d] * fcW[d * 10 + o];
        out[b * 10 + o] = acc * (1.0f / NN) + fcb[o];
    }
}

// ---------------- launch ----------------

extern "C" void kernel_launch(void* const* d_in, const int* in_sizes, int n_in,
                              void* d_out, int out_size, void* d_ws, size_t ws_size,
                              hipStream_t stream) {
    const float* x_in    = (const float*)d_in[0];
    const int*   src     = (const int*)d_in[1];
    const int*   dst     = (const int*)d_in[2];
    const float* W_conv0 = (const float*)d_in[3];
    const float* b_conv0 = (const float*)d_in[4];
    const float* W_convs = (const float*)d_in[5];
    const float* b_convs = (const float*)d_in[6];
    const float* mW1 = (const float*)d_in[7];
    const float* mb1 = (const float*)d_in[8];
    const float* mW2 = (const float*)d_in[9];
    const float* mb2 = (const float*)d_in[10];
    const float* mW3 = (const float*)d_in[11];
    const float* mb3 = (const float*)d_in[12];
    const float* ln1_g = (const float*)d_in[13];
    const float* ln1_b = (const float*)d_in[14];
    const float* ln2_g = (const float*)d_in[15];
    const float* ln2_b = (const float*)d_in[16];
    const float* attnW = (const float*)d_in[17];
    const float* attnu = (const float*)d_in[18];
    const float* fW1 = (const float*)d_in[19];
    const float* fb1 = (const float*)d_in[20];
    const float* fW2 = (const float*)d_in[21];
    const float* fb2 = (const float*)d_in[22];
    const float* fcW = (const float*)d_in[23];
    const float* fcb = (const float*)d_in[24];
    float* out = (float*)d_out;

    // ---- workspace carve ----
    char* p = (char*)d_ws;
    auto alloc = [&](size_t bytes) { char* q = p; p += (bytes + 255) & ~(size_t)255; return q; };
    float* A = (float*)alloc((size_t)MR * DM * 4);                        // fp32 h stream
    unsigned short* sup16 = (unsigned short*)alloc((size_t)MR * DM * 2);  // node-major sup / h1
    unsigned short* act16 = (unsigned short*)alloc((size_t)MR * DM * 2);  // x bf16
    unsigned short* b16   = (unsigned short*)alloc((size_t)MR * DM * 2);  // LN1 output
    unsigned short* t1    = (unsigned short*)alloc((size_t)MR * 128 * 2);
    unsigned short* t2    = (unsigned short*)alloc((size_t)MR * 64 * 2);
    unsigned short* wt    = (unsigned short*)alloc((size_t)548864 * 2);
    float* a_score = (float*)alloc((size_t)MR * 4);
    float* rbuf = (float*)alloc(NB * DM * 4);
    float* pm0  = (float*)alloc(NB * NCH * 4);
    float* pl0  = (float*)alloc(NB * NCH * 4);
    float* pv0  = (float*)alloc((size_t)NB * NCH * DM * 4);
    float* colsum = (float*)alloc(NB * DM * 4);
    int* counts   = (int*)alloc(NN * 4);
    int* row_ptr  = (int*)alloc((NN + 1) * 4);
    int* fill_pos = (int*)alloc(NN * 4);
    int* csr_src  = (int*)alloc(NE * 4);

    unsigned short* Wt_conv0 = wt;                       // 256x128
    unsigned short* Wt_convs = Wt_conv0 + 32768;         // 3 x 256x256
    unsigned short* mW1t = Wt_convs + 196608;            // 128x256
    unsigned short* mW2t = mW1t + 32768;                 // 64x128
    unsigned short* mW3t = mW2t + 8192;                  // 256x64
    unsigned short* fW1t = mW3t + 16384;                 // 2 x 256x256
    unsigned short* fW2t = fW1t + 131072;                // 2 x 256x256

    const dim3 blk(256);

    // ---- CSR build (by dst) ----
    zero_i32_kernel<<<(NN + 255) / 256, blk, 0, stream>>>(counts, NN);
    hist_kernel<<<(NE + 255) / 256, blk, 0, stream>>>(dst, counts, NE);
    scan_kernel<<<1, blk, 0, stream>>>(counts, row_ptr, fill_pos, NN);
    fill_kernel<<<(NE + 255) / 256, blk, 0, stream>>>(src, dst, fill_pos, csr_src, NE);

    // ---- weight transposes ----
    TDs tds;
    tds.d[0]  = {W_conv0, Wt_conv0, 128, 256};
    tds.d[1]  = {W_convs + 0 * 65536, Wt_convs + 0 * 65536, 256, 256};
    tds.d[2]  = {W_convs + 1 * 65536, Wt_convs + 1 * 65536, 256, 256};
    tds.d[3]  = {W_convs + 2 * 65536, Wt_convs + 2 * 65536, 256, 256};
    tds.d[4]  = {mW1, mW1t, 256, 128};
    tds.d[5]  = {mW2, mW2t, 128, 64};
    tds.d[6]  = {mW3, mW3t, 64, 256};
    tds.d[7]  = {fW1 + 0 * 65536, fW1t + 0 * 65536, 256, 256};
    tds.d[8]  = {fW1 + 1 * 65536, fW1t + 1 * 65536, 256, 256};
    tds.d[9]  = {fW2 + 0 * 65536, fW2t + 0 * 65536, 256, 256};
    tds.d[10] = {fW2 + 1 * 65536, fW2t + 1 * 65536, 256, 256};
    transpose_all_kernel<<<dim3(256, 11), blk, 0, stream>>>(tds);

    cvt_bf16_kernel<<<(MR * 128 + 255) / 256, blk, 0, stream>>>(x_in, t1, MR * 128);

    // ---- GCN layers (GEMM writes node-major sup16; agg emits row-major bf16) ----
    mfma_gemm_kernel<128, 2><<<dim3(2, MR / 64), blk, 0, stream>>>(t1, Wt_conv0, nullptr, sup16, 128, 256, 0);
    agg_kernel<<<NN / 2, blk, 0, stream>>>(sup16, row_ptr, csr_src, b_conv0, act16);
    for (int i = 0; i < 3; i++) {
        mfma_gemm_kernel<128, 2><<<dim3(2, MR / 64), blk, 0, stream>>>(act16, Wt_convs + (size_t)i * 65536, nullptr, sup16, 256, 256, 0);
        agg_kernel<<<NN / 2, blk, 0, stream>>>(sup16, row_ptr, csr_src, b_convs + (size_t)i * 256, act16);
    }

    // ---- MLP ----
    mfma_gemm_kernel<128, 1><<<dim3(1, MR / 64), blk, 0, stream>>>(act16, mW1t, mb1, t1, 256, 128, 1);
    mfma_gemm_kernel<64, 1><<<dim3(1, MR / 64), blk, 0, stream>>>(t1, mW2t, mb2, t2, 128, 64, 1);
    mfma_gemm_kernel<128, 1><<<dim3(2, MR / 64), blk, 0, stream>>>(t2, mW3t, mb3, act16, 64, 256, 0);

    // ---- 2 attention/FFN blocks; x bf16 in act16 ----
    const dim3 poolGrid(NCH, NB);
    for (int i = 0; i < 2; i++) {
        const float* Wp = attnW + (size_t)i * DM * 8;
        const float* up = attnu + (size_t)i * 8;
        attn_score_kernel<<<MR / 4, blk, 0, stream>>>(act16, Wp, up, a_score);
        attn_pool_kernel<<<poolGrid, blk, 0, stream>>>(act16, a_score, pm0, pl0, pv0);
        attn_combine_kernel<<<NB, blk, 0, stream>>>(pm0, pl0, pv0, rbuf);
        for (int it = 0; it < 3; it++) {
            dot_kernel<<<MR / 4, blk, 0, stream>>>(act16, rbuf, a_score);
            attn_pool_kernel<<<poolGrid, blk, 0, stream>>>(act16, a_score, pm0, pl0, pv0);
            attn_combine_kernel<<<NB, blk, 0, stream>>>(pm0, pl0, pv0, rbuf);
        }
        // x1 = LN(x + r) -> b16
        ln_bcast_kernel<<<MR / 4, blk, 0, stream>>>(act16, rbuf, ln1_g + (size_t)i * DM,
                                                    ln1_b + (size_t)i * DM, b16);
        // h1 = relu(x1 @ fW1 + fb1) -> sup16 (row-major bf16)
        mfma_gemm_kernel<128, 1><<<dim3(2, MR / 64), blk, 0, stream>>>(b16, fW1t + (size_t)i * 65536,
                                                                       fb1 + (size_t)i * DM, sup16, 256, 256, 1);
        // h2 = h1 @ fW2 + fb2 -> A (fp32)
        mfma_gemm_kernel<128, 0><<<dim3(2, MR / 64), blk, 0, stream>>>(sup16, fW2t + (size_t)i * 65536,
                                                                       fb2 + (size_t)i * DM, A, 256, 256, 0);
        // x = LN(x1 + h2) -> act16
        ln_elem_kernel<<<MR / 4, blk, 0, stream>>>(b16, A, ln2_g + (size_t)i * DM,
                                                   ln2_b + (size_t)i * DM, act16);
    }

    // ---- final: mean over nodes commutes with the linear layer ----
    zero_f32_kernel<<<4, blk, 0, stream>>>(colsum, NB * DM);
    colsum_kernel<<<poolGrid, blk, 0, stream>>>(act16, colsum);
    final_kernel<<<NB, dim3(64), 0, stream>>>(colsum, fcW, fcb, out);
}